// Round 2
// baseline (19347.354 us; speedup 1.0000x reference)
//
#include <hip/hip_runtime.h>
#include <hip/hip_cooperative_groups.h>
#include <math.h>

namespace cg = cooperative_groups;

// Problem constants
#define TX 64
#define BN 64
#define TY 32
#define EE 256
#define HH 512
#define H3 1536
#define KYV 32000

typedef __attribute__((ext_vector_type(8))) short bf16x8;
typedef __attribute__((ext_vector_type(4))) float f32x4;
typedef __attribute__((ext_vector_type(4))) short s16x4;

__device__ __forceinline__ float4 ldf4(const float* p) { return *(const float4*)p; }
__device__ __forceinline__ float sigf(float x) { return 1.f / (1.f + expf(-x)); }

// round-to-nearest-even fp32 -> bf16 bits
__device__ __forceinline__ short f2bf(float x) {
    unsigned u = __float_as_uint(x);
    unsigned r = (u + 0x7fffu + ((u >> 16) & 1u)) >> 16;
    return (short)r;
}
__device__ __forceinline__ float bf2f(short h) {
    return __uint_as_float(((unsigned)(unsigned short)h) << 16);
}

// ---------------------------------------------------------------------------
// Generic NT GEMM (fp32): C[M x N] = A[M x K] * B[N x K]^T (+bias), optional
// A row gather. Tiles 64x64, K-tile 32. M,N % 64 == 0, K % 32 == 0.
// ---------------------------------------------------------------------------
__global__ __launch_bounds__(256) void gemm_nt_kernel(
    const float* __restrict__ Abase, const int* __restrict__ gather, int lda,
    const float* __restrict__ Bbase, int ldb, int bofs,
    const float* __restrict__ bias, float* __restrict__ C, int ldc, int K)
{
    __shared__ float As[32][68];
    __shared__ float Bs[32][68];
    const int tid = threadIdx.x;
    const int n0 = blockIdx.x * 64;
    const int m0 = blockIdx.y * 64;
    const int tx = tid & 15, ty = tid >> 4;
    const int li = tid >> 2, lk = (tid & 3) * 8;
    float acc[4][4] = {};
    const float* arow = gather ? (Abase + (size_t)gather[m0 + li] * lda)
                               : (Abase + (size_t)(m0 + li) * lda);
    const float* brow = Bbase + (size_t)(n0 + li) * ldb + bofs;
    for (int kt = 0; kt < K; kt += 32) {
        float4 a0 = ldf4(arow + kt + lk);
        float4 a1 = ldf4(arow + kt + lk + 4);
        float4 b0 = ldf4(brow + kt + lk);
        float4 b1 = ldf4(brow + kt + lk + 4);
        __syncthreads();
        As[lk+0][li]=a0.x; As[lk+1][li]=a0.y; As[lk+2][li]=a0.z; As[lk+3][li]=a0.w;
        As[lk+4][li]=a1.x; As[lk+5][li]=a1.y; As[lk+6][li]=a1.z; As[lk+7][li]=a1.w;
        Bs[lk+0][li]=b0.x; Bs[lk+1][li]=b0.y; Bs[lk+2][li]=b0.z; Bs[lk+3][li]=b0.w;
        Bs[lk+4][li]=b1.x; Bs[lk+5][li]=b1.y; Bs[lk+6][li]=b1.z; Bs[lk+7][li]=b1.w;
        __syncthreads();
        #pragma unroll
        for (int k = 0; k < 32; ++k) {
            float4 av = *(const float4*)&As[k][ty*4];
            float4 bv = *(const float4*)&Bs[k][tx*4];
            acc[0][0] += av.x*bv.x; acc[0][1] += av.x*bv.y; acc[0][2] += av.x*bv.z; acc[0][3] += av.x*bv.w;
            acc[1][0] += av.y*bv.x; acc[1][1] += av.y*bv.y; acc[1][2] += av.y*bv.z; acc[1][3] += av.y*bv.w;
            acc[2][0] += av.z*bv.x; acc[2][1] += av.z*bv.y; acc[2][2] += av.z*bv.z; acc[2][3] += av.z*bv.w;
            acc[3][0] += av.w*bv.x; acc[3][1] += av.w*bv.y; acc[3][2] += av.w*bv.z; acc[3][3] += av.w*bv.w;
        }
    }
    #pragma unroll
    for (int ii = 0; ii < 4; ++ii) {
        int r = m0 + ty*4 + ii;
        #pragma unroll
        for (int jj = 0; jj < 4; ++jj) {
            int c = n0 + tx*4 + jj;
            float v = acc[ii][jj];
            if (bias) v += bias[c];
            C[(size_t)r*ldc + c] = v;
        }
    }
}

// ---------------------------------------------------------------------------
// Split fp32 W into bf16 hi/lo planes (once per launch).
// ---------------------------------------------------------------------------
__global__ __launch_bounds__(256) void wsplit_kernel(
    const float* __restrict__ W, short* __restrict__ hi, short* __restrict__ lo,
    long n4)
{
    for (long i = (long)blockIdx.x*blockDim.x + threadIdx.x; i < n4;
         i += (long)gridDim.x*blockDim.x) {
        float4 v = ((const float4*)W)[i];
        s16x4 h, l;
        h.x = f2bf(v.x); l.x = f2bf(v.x - bf2f(h.x));
        h.y = f2bf(v.y); l.y = f2bf(v.y - bf2f(h.y));
        h.z = f2bf(v.z); l.z = f2bf(v.z - bf2f(h.z));
        h.w = f2bf(v.w); l.w = f2bf(v.w - bf2f(h.w));
        ((s16x4*)hi)[i] = h;
        ((s16x4*)lo)[i] = l;
    }
}

// ---------------------------------------------------------------------------
// Cooperative encoder scan: all 64 timesteps, both directions, grid.sync
// between steps. 256 blocks x 256 thr (1 block/CU). Same math/layout as the
// old enc_step_kernel.
// ---------------------------------------------------------------------------
__global__ __launch_bounds__(256) void enc_scan_kernel(
    const float* __restrict__ GI_f, const float* __restrict__ GI_b,
    const float* __restrict__ Whh_f, const float* __restrict__ bhh_f,
    const float* __restrict__ Whh_b, const float* __restrict__ bhh_b,
    float* __restrict__ hf, float* __restrict__ hb,
    float* __restrict__ enc_out)
{
    cg::grid_group grid = cg::this_grid();
    const int blk = blockIdx.x;
    const int dir = blk >> 7;
    const int r = blk & 127;
    const int cgp = r >> 1;
    const int bh = r & 1;
    const int sub = threadIdx.x >> 5;
    const int b = bh*32 + (threadIdx.x & 31);
    const int col = cgp*8 + sub;

    const float* GI = dir ? GI_b : GI_f;
    const float* W  = dir ? Whh_b : Whh_f;
    const float* bhv = dir ? bhh_b : bhh_f;
    float* hbase = dir ? hb : hf;

    const float* wr = W + (size_t)col*HH;
    const float* wz = W + (size_t)(HH + col)*HH;
    const float* wn = W + (size_t)(2*HH + col)*HH;
    const float brc = bhv[col], bzc = bhv[HH + col], bnc = bhv[2*HH + col];

    for (int t = 0; t < TX; ++t) {
        const float* hrow = hbase + (t & 1)*BN*HH + b*HH;
        float* hout = hbase + ((t + 1) & 1)*BN*HH;
        const int tstep = dir ? (TX-1-t) : t;
        float ar = 0.f, az = 0.f, an = 0.f;
        for (int k = 0; k < HH; k += 4) {
            float4 hv = ldf4(hrow + k);
            float4 A = ldf4(wr + k), Z = ldf4(wz + k), N = ldf4(wn + k);
            ar += hv.x*A.x + hv.y*A.y + hv.z*A.z + hv.w*A.w;
            az += hv.x*Z.x + hv.y*Z.y + hv.z*Z.z + hv.w*Z.w;
            an += hv.x*N.x + hv.y*N.y + hv.z*N.z + hv.w*N.w;
        }
        size_t gbase = ((size_t)tstep*BN + b) * H3;
        float ir = GI[gbase + col];
        float iz = GI[gbase + HH + col];
        float inn = GI[gbase + 2*HH + col];
        float rr = sigf(ir + ar + brc);
        float zz = sigf(iz + az + bzc);
        float nn = tanhf(inn + rr*(an + bnc));
        float hold = hrow[col];
        float h2 = (1.f - zz)*nn + zz*hold;
        hout[b*HH + col] = h2;
        enc_out[((size_t)tstep*BN + b)*(2*HH) + dir*HH + col] = h2;
        grid.sync();
    }
}

// ---------------------------------------------------------------------------
// Decoder init: hidden = tanh(h_b_final @ W_init.T + b_init); tok = 1
// ---------------------------------------------------------------------------
__global__ __launch_bounds__(256) void dec_init_kernel(
    const float* __restrict__ hbf, const float* __restrict__ Wi,
    const float* __restrict__ bi, float* __restrict__ hdec, int* __restrict__ tok)
{
    const int b = blockIdx.x, tid = threadIdx.x;
    const float* hr = hbf + b*HH;
    for (int n = tid; n < HH; n += 256) {
        float acc = bi[n];
        const float* w = Wi + (size_t)n*HH;
        for (int k = 0; k < HH; k += 4) {
            float4 hv = ldf4(hr + k), wv = ldf4(w + k);
            acc += hv.x*wv.x + hv.y*wv.y + hv.z*wv.z + hv.w*wv.w;
        }
        hdec[b*HH + n] = tanhf(acc);
    }
    if (b == 0 && tid < 64) tok[tid] = 1;
}

// ---------------------------------------------------------------------------
// Cooperative decoder loop: all 32 steps in one kernel.
// Grid 256 blocks x 512 thr (1 block/CU, 8 waves, VGPR<=256 -> co-resident).
// Per step, 6 phases separated by grid.sync():
//   A: qs[b][n]   = h @ Wa1[:, 0:512]^T + ba1      (n split across blocks)
//   B: ss[t][b]   = sum_n Wa2[n]*tanh(qs+P) + ba2
//   C: softmax over t, ctx[b][c], ctx bf16 planes  (4 blocks per b)
//   D: GRU -> h_nxt, h bf16 planes
//   E: logits MFMA (bf16x3, pre-split W planes), 2 tiles/block via 8 waves
//   F: lse/argmax/sub in-place on out row (blocks 0..63)
// ---------------------------------------------------------------------------
__global__ __launch_bounds__(512, 2) void dec_loop_kernel(
    const float* __restrict__ P, const float* __restrict__ enc,
    const float* __restrict__ Wa1, const float* __restrict__ ba1,
    const float* __restrict__ Wa2, const float* __restrict__ ba2,
    const float* __restrict__ demb,
    const float* __restrict__ Wih, const float* __restrict__ Whh,
    const float* __restrict__ bih, const float* __restrict__ bhh,
    const short* __restrict__ Whi, const short* __restrict__ Wlo,
    const float* __restrict__ blsm,
    float* __restrict__ hdec, float* __restrict__ ctx,
    float* __restrict__ qs, float* __restrict__ ss,
    short* __restrict__ Ahi, short* __restrict__ Alo,
    int* __restrict__ tok, float* __restrict__ out)
{
    cg::grid_group grid = cg::this_grid();
    const int B = blockIdx.x;     // 0..255
    const int tid = threadIdx.x;  // 0..511

    __shared__ float ww_s[TX];
    __shared__ float ms8[8], ss8[8];
    __shared__ int   is8[8];
    __shared__ float l_sh;

    for (int s = 0; s < TY; ++s) {
        float* h_cur = hdec + (s & 1)*BN*HH;
        float* h_nxt = hdec + ((s + 1) & 1)*BN*HH;

        // ---------------- Phase A: q projection ----------------
        {
            const int idx = tid >> 2;           // 0..127
            const int quarter = tid & 3;
            const int n = B*2 + (idx >> 6);     // 0..511
            const int b = idx & 63;
            const float* hr = h_cur + b*HH + quarter*128;
            const float* w = Wa1 + (size_t)n*H3 + quarter*128;
            float acc = 0.f;
            for (int k = 0; k < 128; k += 4) {
                float4 hv = ldf4(hr + k), wv = ldf4(w + k);
                acc += hv.x*wv.x + hv.y*wv.y + hv.z*wv.z + hv.w*wv.w;
            }
            acc += __shfl_xor(acc, 1);
            acc += __shfl_xor(acc, 2);
            if (quarter == 0) qs[b*HH + n] = acc + ba1[n];
        }
        grid.sync();

        // ---------------- Phase B: attention scores ----------------
        {
            const int o = B*16 + (tid >> 5);    // 0..4095
            const int t = o >> 6, b = o & 63;
            const int l = tid & 31;
            const float* q = qs + b*HH + l*16;
            const float* p = P + ((size_t)t*BN + b)*HH + l*16;
            const float* w2 = Wa2 + l*16;
            float acc = 0.f;
            #pragma unroll
            for (int k = 0; k < 16; k += 4) {
                float4 qv = ldf4(q + k), pv = ldf4(p + k), wv = ldf4(w2 + k);
                acc += wv.x*tanhf(qv.x + pv.x);
                acc += wv.y*tanhf(qv.y + pv.y);
                acc += wv.z*tanhf(qv.z + pv.z);
                acc += wv.w*tanhf(qv.w + pv.w);
            }
            acc += __shfl_xor(acc, 1);
            acc += __shfl_xor(acc, 2);
            acc += __shfl_xor(acc, 4);
            acc += __shfl_xor(acc, 8);
            acc += __shfl_xor(acc, 16);
            if (l == 0) ss[t*64 + b] = acc + ba2[0];
        }
        grid.sync();

        // ---------------- Phase C: softmax + context ----------------
        {
            const int b = B & 63;
            const int cq = B >> 6;              // 0..3 (c-range group)
            if (tid < 64) {
                float v = ss[tid*64 + b];
                float m = v;
                for (int off = 32; off; off >>= 1) m = fmaxf(m, __shfl_xor(m, off));
                float e = expf(v - m);
                float sm = e;
                for (int off = 32; off; off >>= 1) sm += __shfl_xor(sm, off);
                ww_s[tid] = e / sm;
            }
            __syncthreads();
            if (tid < 256) {
                const int c = cq*256 + tid;
                float acc = 0.f;
                #pragma unroll 8
                for (int t2 = 0; t2 < TX; ++t2)
                    acc += ww_s[t2] * enc[((size_t)t2*BN + b)*(2*HH) + c];
                ctx[b*(2*HH) + c] = acc;
                short hi2 = f2bf(acc);
                Ahi[(size_t)b*H3 + HH + c] = hi2;
                Alo[(size_t)b*H3 + HH + c] = f2bf(acc - bf2f(hi2));
            }
        }
        grid.sync();

        // ---------------- Phase D: decoder GRU ----------------
        {
            const int idx = tid >> 2;           // 0..127
            const int quarter = tid & 3;
            const int col = B*2 + (idx >> 6);   // 0..511
            const int b = idx & 63;
            const float* emb = demb + (size_t)tok[b]*EE + quarter*64;
            const float* cr = ctx + b*(2*HH) + quarter*256;
            const float* hr = h_cur + b*HH + quarter*128;
            float ir = 0.f, iz = 0.f, inn = 0.f;
            float hrr = 0.f, hzz = 0.f, hnn = 0.f;
            {
                const float* wri = Wih + (size_t)col*1280 + quarter*64;
                const float* wzi = Wih + (size_t)(HH + col)*1280 + quarter*64;
                const float* wni = Wih + (size_t)(2*HH + col)*1280 + quarter*64;
                for (int k = 0; k < 64; k += 4) {
                    float4 e = ldf4(emb + k);
                    float4 A = ldf4(wri + k), Z = ldf4(wzi + k), N = ldf4(wni + k);
                    ir  += e.x*A.x + e.y*A.y + e.z*A.z + e.w*A.w;
                    iz  += e.x*Z.x + e.y*Z.y + e.z*Z.z + e.w*Z.w;
                    inn += e.x*N.x + e.y*N.y + e.z*N.z + e.w*N.w;
                }
            }
            {
                const float* wri = Wih + (size_t)col*1280 + EE + quarter*256;
                const float* wzi = Wih + (size_t)(HH + col)*1280 + EE + quarter*256;
                const float* wni = Wih + (size_t)(2*HH + col)*1280 + EE + quarter*256;
                for (int k = 0; k < 256; k += 4) {
                    float4 c = ldf4(cr + k);
                    float4 A = ldf4(wri + k), Z = ldf4(wzi + k), N = ldf4(wni + k);
                    ir  += c.x*A.x + c.y*A.y + c.z*A.z + c.w*A.w;
                    iz  += c.x*Z.x + c.y*Z.y + c.z*Z.z + c.w*Z.w;
                    inn += c.x*N.x + c.y*N.y + c.z*N.z + c.w*N.w;
                }
            }
            {
                const float* wrh = Whh + (size_t)col*HH + quarter*128;
                const float* wzh = Whh + (size_t)(HH + col)*HH + quarter*128;
                const float* wnh = Whh + (size_t)(2*HH + col)*HH + quarter*128;
                for (int k = 0; k < 128; k += 4) {
                    float4 hv = ldf4(hr + k);
                    float4 A = ldf4(wrh + k), Z = ldf4(wzh + k), N = ldf4(wnh + k);
                    hrr += hv.x*A.x + hv.y*A.y + hv.z*A.z + hv.w*A.w;
                    hzz += hv.x*Z.x + hv.y*Z.y + hv.z*Z.z + hv.w*Z.w;
                    hnn += hv.x*N.x + hv.y*N.y + hv.z*N.z + hv.w*N.w;
                }
            }
            ir  += __shfl_xor(ir, 1);  ir  += __shfl_xor(ir, 2);
            iz  += __shfl_xor(iz, 1);  iz  += __shfl_xor(iz, 2);
            inn += __shfl_xor(inn, 1); inn += __shfl_xor(inn, 2);
            hrr += __shfl_xor(hrr, 1); hrr += __shfl_xor(hrr, 2);
            hzz += __shfl_xor(hzz, 1); hzz += __shfl_xor(hzz, 2);
            hnn += __shfl_xor(hnn, 1); hnn += __shfl_xor(hnn, 2);
            if (quarter == 0) {
                float rr = sigf(ir + bih[col] + hrr + bhh[col]);
                float zz = sigf(iz + bih[HH + col] + hzz + bhh[HH + col]);
                float nn = tanhf(inn + bih[2*HH + col] + rr*(hnn + bhh[2*HH + col]));
                float h2 = (1.f - zz)*nn + zz*h_cur[b*HH + col];
                h_nxt[b*HH + col] = h2;
                short hi2 = f2bf(h2);
                Ahi[(size_t)b*H3 + col] = hi2;
                Alo[(size_t)b*H3 + col] = f2bf(h2 - bf2f(hi2));
            }
        }
        grid.sync();

        // ---------------- Phase E: logits MFMA ----------------
        float* lrow = out + (size_t)s*BN*KYV;
        {
            const int wave = tid >> 6;
            const int lane = tid & 63;
            const int tile = (wave < 4) ? B : (B + 256);
            if (tile < 500) {
                const int w4 = wave & 3;
                const int n0 = tile * 64;
                const int m = lane & 15;
                const int q = lane >> 4;
                const short* ah_p = Ahi + (size_t)(w4*16 + m)*H3 + q*8;
                const short* al_p = Alo + (size_t)(w4*16 + m)*H3 + q*8;
                const short* bh_p = Whi + (size_t)(n0 + m)*H3 + q*8;
                const short* bl_p = Wlo + (size_t)(n0 + m)*H3 + q*8;
                f32x4 acc0 = {0,0,0,0}, acc1 = {0,0,0,0}, acc2 = {0,0,0,0}, acc3 = {0,0,0,0};
                for (int kt = 0; kt < H3; kt += 32) {
                    bf16x8 ah = *(const bf16x8*)(ah_p + kt);
                    bf16x8 al = *(const bf16x8*)(al_p + kt);
                    bf16x8 b0h = *(const bf16x8*)(bh_p + kt);
                    bf16x8 b0l = *(const bf16x8*)(bl_p + kt);
                    bf16x8 b1h = *(const bf16x8*)(bh_p + 16*H3 + kt);
                    bf16x8 b1l = *(const bf16x8*)(bl_p + 16*H3 + kt);
                    bf16x8 b2h = *(const bf16x8*)(bh_p + 32*H3 + kt);
                    bf16x8 b2l = *(const bf16x8*)(bl_p + 32*H3 + kt);
                    bf16x8 b3h = *(const bf16x8*)(bh_p + 48*H3 + kt);
                    bf16x8 b3l = *(const bf16x8*)(bl_p + 48*H3 + kt);
                    acc0 = __builtin_amdgcn_mfma_f32_16x16x32_bf16(ah, b0h, acc0, 0, 0, 0);
                    acc0 = __builtin_amdgcn_mfma_f32_16x16x32_bf16(al, b0h, acc0, 0, 0, 0);
                    acc0 = __builtin_amdgcn_mfma_f32_16x16x32_bf16(ah, b0l, acc0, 0, 0, 0);
                    acc1 = __builtin_amdgcn_mfma_f32_16x16x32_bf16(ah, b1h, acc1, 0, 0, 0);
                    acc1 = __builtin_amdgcn_mfma_f32_16x16x32_bf16(al, b1h, acc1, 0, 0, 0);
                    acc1 = __builtin_amdgcn_mfma_f32_16x16x32_bf16(ah, b1l, acc1, 0, 0, 0);
                    acc2 = __builtin_amdgcn_mfma_f32_16x16x32_bf16(ah, b2h, acc2, 0, 0, 0);
                    acc2 = __builtin_amdgcn_mfma_f32_16x16x32_bf16(al, b2h, acc2, 0, 0, 0);
                    acc2 = __builtin_amdgcn_mfma_f32_16x16x32_bf16(ah, b2l, acc2, 0, 0, 0);
                    acc3 = __builtin_amdgcn_mfma_f32_16x16x32_bf16(ah, b3h, acc3, 0, 0, 0);
                    acc3 = __builtin_amdgcn_mfma_f32_16x16x32_bf16(al, b3h, acc3, 0, 0, 0);
                    acc3 = __builtin_amdgcn_mfma_f32_16x16x32_bf16(ah, b3l, acc3, 0, 0, 0);
                }
                const int row = w4*16 + q*4;
                #pragma unroll
                for (int r = 0; r < 4; ++r) {
                    size_t ro = (size_t)(row + r)*KYV;
                    lrow[ro + n0 +  0 + m] = acc0[r] + blsm[n0 +  0 + m];
                    lrow[ro + n0 + 16 + m] = acc1[r] + blsm[n0 + 16 + m];
                    lrow[ro + n0 + 32 + m] = acc2[r] + blsm[n0 + 32 + m];
                    lrow[ro + n0 + 48 + m] = acc3[r] + blsm[n0 + 48 + m];
                }
            }
        }
        grid.sync();

        // ---------------- Phase F: lse + argmax + subtract ----------------
        if (B < 64) {
            float4* row4 = (float4*)(lrow + (size_t)B*KYV);
            float m = -1e30f, sacc = 0.f; int bi = 0;
            for (int i = tid; i < KYV/4; i += 512) {
                float4 v = row4[i];
                if (v.x > m) { sacc = sacc*expf(m - v.x) + 1.f; m = v.x; bi = 4*i+0; } else sacc += expf(v.x - m);
                if (v.y > m) { sacc = sacc*expf(m - v.y) + 1.f; m = v.y; bi = 4*i+1; } else sacc += expf(v.y - m);
                if (v.z > m) { sacc = sacc*expf(m - v.z) + 1.f; m = v.z; bi = 4*i+2; } else sacc += expf(v.z - m);
                if (v.w > m) { sacc = sacc*expf(m - v.w) + 1.f; m = v.w; bi = 4*i+3; } else sacc += expf(v.w - m);
            }
            for (int off = 32; off; off >>= 1) {
                float m2 = __shfl_xor(m, off);
                float s2 = __shfl_xor(sacc, off);
                int i2 = __shfl_xor(bi, off);
                if (m2 > m || (m2 == m && i2 < bi)) { sacc = s2 + sacc*expf(m - m2); m = m2; bi = i2; }
                else sacc = sacc + s2*expf(m2 - m);
            }
            const int wid = tid >> 6;
            if ((tid & 63) == 0) { ms8[wid] = m; ss8[wid] = sacc; is8[wid] = bi; }
            __syncthreads();
            if (tid == 0) {
                for (int w = 1; w < 8; ++w) {
                    float m2 = ms8[w], s2 = ss8[w]; int i2 = is8[w];
                    if (m2 > m || (m2 == m && i2 < bi)) { sacc = s2 + sacc*expf(m - m2); m = m2; bi = i2; }
                    else sacc = sacc + s2*expf(m2 - m);
                }
                l_sh = m + logf(sacc);
                tok[B] = bi;
            }
            __syncthreads();
            const float l = l_sh;
            for (int i = tid; i < KYV/4; i += 512) {
                float4 v = row4[i];
                v.x -= l; v.y -= l; v.z -= l; v.w -= l;
                row4[i] = v;
            }
        }
        grid.sync();
    }
}

// ===========================================================================
// ======================= Fallback (round-1) kernels ========================
// ===========================================================================

__global__ __launch_bounds__(256) void enc_step_kernel(
    const float* __restrict__ GI_f, const float* __restrict__ GI_b,
    const float* __restrict__ Whh_f, const float* __restrict__ bhh_f,
    const float* __restrict__ Whh_b, const float* __restrict__ bhh_b,
    const float* __restrict__ hf_in, float* __restrict__ hf_out,
    const float* __restrict__ hb_in, float* __restrict__ hb_out,
    float* __restrict__ enc_out, int t)
{
    const int blk = blockIdx.x;
    const int dir = blk >> 7;
    const int r = blk & 127;
    const int cgp = r >> 1;
    const int bh = r & 1;
    const int sub = threadIdx.x >> 5;
    const int b = bh*32 + (threadIdx.x & 31);
    const int col = cgp*8 + sub;

    const float* GI = dir ? GI_b : GI_f;
    const float* W  = dir ? Whh_b : Whh_f;
    const float* bh_v = dir ? bhh_b : bhh_f;
    const float* hin  = dir ? hb_in : hf_in;
    float* hout = dir ? hb_out : hf_out;
    const int tstep = dir ? (TX-1-t) : t;

    const float* hrow = hin + b*HH;
    const float* wr = W + (size_t)col*HH;
    const float* wz = W + (size_t)(HH + col)*HH;
    const float* wn = W + (size_t)(2*HH + col)*HH;
    float ar = 0.f, az = 0.f, an = 0.f;
    for (int k = 0; k < HH; k += 4) {
        float4 hv = ldf4(hrow + k);
        float4 A = ldf4(wr + k), Z = ldf4(wz + k), N = ldf4(wn + k);
        ar += hv.x*A.x + hv.y*A.y + hv.z*A.z + hv.w*A.w;
        az += hv.x*Z.x + hv.y*Z.y + hv.z*Z.z + hv.w*Z.w;
        an += hv.x*N.x + hv.y*N.y + hv.z*N.z + hv.w*N.w;
    }
    size_t gbase = ((size_t)tstep*BN + b) * H3;
    float ir = GI[gbase + col];
    float iz = GI[gbase + HH + col];
    float inn = GI[gbase + 2*HH + col];
    float rr = sigf(ir + ar + bh_v[col]);
    float zz = sigf(iz + az + bh_v[HH + col]);
    float nn = tanhf(inn + rr*(an + bh_v[2*HH + col]));
    float hold = hrow[col];
    float h2 = (1.f - zz)*nn + zz*hold;
    hout[b*HH + col] = h2;
    enc_out[((size_t)tstep*BN + b)*(2*HH) + dir*HH + col] = h2;
}

__global__ __launch_bounds__(256) void attn_kernel(
    const float* __restrict__ h, const float* __restrict__ P,
    const float* __restrict__ enc, const float* __restrict__ Wa1,
    const float* __restrict__ ba1, const float* __restrict__ Wa2,
    const float* __restrict__ ba2, float* __restrict__ ctx,
    short* __restrict__ Ahi, short* __restrict__ Alo)
{
    __shared__ float hs[HH];
    __shared__ float qsl[HH];
    __shared__ float ssl[TX];
    __shared__ float ww[TX];
    const int b = blockIdx.x, tid = threadIdx.x;
    hs[tid] = h[b*HH + tid];
    hs[tid + 256] = h[b*HH + 256 + tid];
    __syncthreads();
    for (int n = tid; n < HH; n += 256) {
        float acc = ba1[n];
        const float* w = Wa1 + (size_t)n*H3;
        for (int k = 0; k < HH; k += 4) {
            float4 wv = ldf4(w + k);
            acc += hs[k]*wv.x + hs[k+1]*wv.y + hs[k+2]*wv.z + hs[k+3]*wv.w;
        }
        qsl[n] = acc;
    }
    __syncthreads();
    {
        const int t = tid >> 2, part = tid & 3;
        const float* p = P + ((size_t)t*BN + b)*HH + part*128;
        const float* w2 = Wa2 + part*128;
        const float* q = qsl + part*128;
        float acc = 0.f;
        for (int k = 0; k < 128; k += 4) {
            float4 pv = ldf4(p + k), wv = ldf4(w2 + k);
            acc += wv.x*tanhf(q[k+0] + pv.x);
            acc += wv.y*tanhf(q[k+1] + pv.y);
            acc += wv.z*tanhf(q[k+2] + pv.z);
            acc += wv.w*tanhf(q[k+3] + pv.w);
        }
        acc += __shfl_xor(acc, 1);
        acc += __shfl_xor(acc, 2);
        if (part == 0) ssl[t] = acc + ba2[0];
    }
    __syncthreads();
    if (tid < 64) {
        float v = ssl[tid];
        float m = v;
        for (int off = 32; off; off >>= 1) m = fmaxf(m, __shfl_xor(m, off));
        float e = expf(v - m);
        float sm = e;
        for (int off = 32; off; off >>= 1) sm += __shfl_xor(sm, off);
        ww[tid] = e / sm;
    }
    __syncthreads();
    for (int c = tid; c < 2*HH; c += 256) {
        float acc = 0.f;
        #pragma unroll 4
        for (int t2 = 0; t2 < TX; ++t2)
            acc += ww[t2] * enc[((size_t)t2*BN + b)*(2*HH) + c];
        ctx[b*(2*HH) + c] = acc;
        short hi = f2bf(acc);
        Ahi[(size_t)b*H3 + HH + c] = hi;
        Alo[(size_t)b*H3 + HH + c] = f2bf(acc - bf2f(hi));
    }
}

__global__ __launch_bounds__(256) void dec_gru_kernel(
    const float* __restrict__ demb, const int* __restrict__ tok,
    const float* __restrict__ ctx, const float* __restrict__ h,
    const float* __restrict__ Wih, const float* __restrict__ Whh,
    const float* __restrict__ bih, const float* __restrict__ bhh,
    float* __restrict__ hout, short* __restrict__ Ahi, short* __restrict__ Alo)
{
    const int col = blockIdx.x*4 + (threadIdx.x >> 6);
    const int b = threadIdx.x & 63;
    const float* emb = demb + (size_t)tok[b]*EE;
    const float* cr = ctx + b*(2*HH);
    const float* hr = h + b*HH;
    const float* wri = Wih + (size_t)col*1280;
    const float* wzi = Wih + (size_t)(HH + col)*1280;
    const float* wni = Wih + (size_t)(2*HH + col)*1280;
    float ir = 0.f, iz = 0.f, inn = 0.f;
    for (int k = 0; k < EE; k += 4) {
        float4 e = ldf4(emb + k);
        float4 A = ldf4(wri + k), Z = ldf4(wzi + k), N = ldf4(wni + k);
        ir  += e.x*A.x + e.y*A.y + e.z*A.z + e.w*A.w;
        iz  += e.x*Z.x + e.y*Z.y + e.z*Z.z + e.w*Z.w;
        inn += e.x*N.x + e.y*N.y + e.z*N.z + e.w*N.w;
    }
    for (int k = 0; k < 2*HH; k += 4) {
        float4 c = ldf4(cr + k);
        float4 A = ldf4(wri + EE + k), Z = ldf4(wzi + EE + k), N = ldf4(wni + EE + k);
        ir  += c.x*A.x + c.y*A.y + c.z*A.z + c.w*A.w;
        iz  += c.x*Z.x + c.y*Z.y + c.z*Z.z + c.w*Z.w;
        inn += c.x*N.x + c.y*N.y + c.z*N.z + c.w*N.w;
    }
    const float* wrh = Whh + (size_t)col*HH;
    const float* wzh = Whh + (size_t)(HH + col)*HH;
    const float* wnh = Whh + (size_t)(2*HH + col)*HH;
    float hrr = 0.f, hzz = 0.f, hnn = 0.f;
    for (int k = 0; k < HH; k += 4) {
        float4 hv = ldf4(hr + k);
        float4 A = ldf4(wrh + k), Z = ldf4(wzh + k), N = ldf4(wnh + k);
        hrr += hv.x*A.x + hv.y*A.y + hv.z*A.z + hv.w*A.w;
        hzz += hv.x*Z.x + hv.y*Z.y + hv.z*Z.z + hv.w*Z.w;
        hnn += hv.x*N.x + hv.y*N.y + hv.z*N.z + hv.w*N.w;
    }
    float rr = sigf(ir + bih[col] + hrr + bhh[col]);
    float zz = sigf(iz + bih[HH + col] + hzz + bhh[HH + col]);
    float nn = tanhf(inn + bih[2*HH + col] + rr*(hnn + bhh[2*HH + col]));
    float hv0 = hr[col];
    float h2 = (1.f - zz)*nn + zz*hv0;
    hout[b*HH + col] = h2;
    short hi = f2bf(h2);
    Ahi[(size_t)b*H3 + col] = hi;
    Alo[(size_t)b*H3 + col] = f2bf(h2 - bf2f(hi));
}

// On-the-fly split logits (fallback when ws can't hold W planes).
__global__ __launch_bounds__(256) void logits_mfma_otf_kernel(
    const short* __restrict__ Ahi, const short* __restrict__ Alo,
    const float* __restrict__ W, const float* __restrict__ blsm,
    float* __restrict__ outrow)
{
    const int wave = threadIdx.x >> 6;
    const int lane = threadIdx.x & 63;
    const int n0 = blockIdx.x * 64;
    const int m = lane & 15;
    const int q = lane >> 4;

    const short* arow_h = Ahi + (size_t)(wave*16 + m)*H3 + q*8;
    const short* arow_l = Alo + (size_t)(wave*16 + m)*H3 + q*8;
    const float* brow = W + (size_t)(n0 + m)*H3 + q*8;

    f32x4 acc[4] = {{0,0,0,0},{0,0,0,0},{0,0,0,0},{0,0,0,0}};
    for (int kt = 0; kt < H3; kt += 32) {
        bf16x8 ah = *(const bf16x8*)(arow_h + kt);
        bf16x8 al = *(const bf16x8*)(arow_l + kt);
        float4 w0[4], w1[4];
        #pragma unroll
        for (int t = 0; t < 4; ++t) {
            const float* bp = brow + (size_t)(16*t)*H3 + kt;
            w0[t] = ldf4(bp);
            w1[t] = ldf4(bp + 4);
        }
        #pragma unroll
        for (int t = 0; t < 4; ++t) {
            float f[8] = {w0[t].x, w0[t].y, w0[t].z, w0[t].w,
                          w1[t].x, w1[t].y, w1[t].z, w1[t].w};
            bf16x8 bh, bl;
            #pragma unroll
            for (int j = 0; j < 8; ++j) {
                unsigned u = __float_as_uint(f[j]);
                unsigned hu = u & 0xffff0000u;
                bh[j] = (short)(hu >> 16);
                bl[j] = f2bf(f[j] - __uint_as_float(hu));
            }
            acc[t] = __builtin_amdgcn_mfma_f32_16x16x32_bf16(ah, bh, acc[t], 0, 0, 0);
            acc[t] = __builtin_amdgcn_mfma_f32_16x16x32_bf16(al, bh, acc[t], 0, 0, 0);
            acc[t] = __builtin_amdgcn_mfma_f32_16x16x32_bf16(ah, bl, acc[t], 0, 0, 0);
        }
    }
    const int row = wave*16 + q*4;
    #pragma unroll
    for (int r = 0; r < 4; ++r) {
        size_t ro = (size_t)(row + r)*KYV;
        outrow[ro + n0 +  0 + m] = acc[0][r] + blsm[n0 +  0 + m];
        outrow[ro + n0 + 16 + m] = acc[1][r] + blsm[n0 + 16 + m];
        outrow[ro + n0 + 32 + m] = acc[2][r] + blsm[n0 + 32 + m];
        outrow[ro + n0 + 48 + m] = acc[3][r] + blsm[n0 + 48 + m];
    }
}

__global__ __launch_bounds__(256) void lse_argmax_sub_kernel(
    float* __restrict__ rows, int* __restrict__ tok)
{
    const int b = blockIdx.x, tid = threadIdx.x;
    float4* row4 = (float4*)(rows + (size_t)b*KYV);
    float m = -1e30f, s = 0.f; int bi = 0;
    for (int i = tid; i < KYV/4; i += 256) {
        float4 v = row4[i];
        if (v.x > m) { s = s*expf(m - v.x) + 1.f; m = v.x; bi = 4*i+0; } else s += expf(v.x - m);
        if (v.y > m) { s = s*expf(m - v.y) + 1.f; m = v.y; bi = 4*i+1; } else s += expf(v.y - m);
        if (v.z > m) { s = s*expf(m - v.z) + 1.f; m = v.z; bi = 4*i+2; } else s += expf(v.z - m);
        if (v.w > m) { s = s*expf(m - v.w) + 1.f; m = v.w; bi = 4*i+3; } else s += expf(v.w - m);
    }
    for (int off = 32; off; off >>= 1) {
        float m2 = __shfl_xor(m, off);
        float s2 = __shfl_xor(s, off);
        int i2 = __shfl_xor(bi, off);
        if (m2 > m || (m2 == m && i2 < bi)) { s = s2 + s*expf(m - m2); m = m2; bi = i2; }
        else s = s + s2*expf(m2 - m);
    }
    __shared__ float ms[4], ssh[4];
    __shared__ int is_[4];
    __shared__ float l_sh;
    const int wid = tid >> 6;
    if ((tid & 63) == 0) { ms[wid] = m; ssh[wid] = s; is_[wid] = bi; }
    __syncthreads();
    if (tid == 0) {
        for (int w = 1; w < 4; ++w) {
            float m2 = ms[w], s2 = ssh[w]; int i2 = is_[w];
            if (m2 > m || (m2 == m && i2 < bi)) { s = s2 + s*expf(m - m2); m = m2; bi = i2; }
            else s = s + s2*expf(m2 - m);
        }
        l_sh = m + logf(s);
        tok[b] = bi;
    }
    __syncthreads();
    const float l = l_sh;
    for (int i = tid; i < KYV/4; i += 256) {
        float4 v = row4[i];
        v.x -= l; v.y -= l; v.z -= l; v.w -= l;
        row4[i] = v;
    }
}

// ---------------------------------------------------------------------------
extern "C" void kernel_launch(void* const* d_in, const int* in_sizes, int n_in,
                              void* d_out, int out_size, void* d_ws, size_t ws_size,
                              hipStream_t stream)
{
    const int*   inputs  = (const int*)  d_in[0];
    const float* enc_emb = (const float*)d_in[2];
    const float* W_ih_f  = (const float*)d_in[3];
    const float* W_hh_f  = (const float*)d_in[4];
    const float* b_ih_f  = (const float*)d_in[5];
    const float* b_hh_f  = (const float*)d_in[6];
    const float* W_ih_b  = (const float*)d_in[7];
    const float* W_hh_b  = (const float*)d_in[8];
    const float* b_ih_b  = (const float*)d_in[9];
    const float* b_hh_b  = (const float*)d_in[10];
    const float* W_init  = (const float*)d_in[11];
    const float* b_init  = (const float*)d_in[12];
    const float* dec_emb = (const float*)d_in[13];
    const float* W_ih_d  = (const float*)d_in[14];
    const float* W_hh_d  = (const float*)d_in[15];
    const float* b_ih_d  = (const float*)d_in[16];
    const float* b_hh_d  = (const float*)d_in[17];
    const float* W_lsm   = (const float*)d_in[18];
    const float* b_lsm   = (const float*)d_in[19];
    const float* W_a1    = (const float*)d_in[20];
    const float* b_a1    = (const float*)d_in[21];
    const float* W_a2    = (const float*)d_in[22];
    const float* b_a2    = (const float*)d_in[23];

    float* ws = (float*)d_ws;
    float* GI_f   = ws;
    float* GI_b   = GI_f + (size_t)4096*1536;
    float* enc_out= GI_b + (size_t)4096*1536;
    float* P_enc  = enc_out + (size_t)4096*1024;
    float* hf     = P_enc + (size_t)4096*512;
    float* hb     = hf + 2*BN*HH;
    float* hdec   = hb + 2*BN*HH;
    float* ctx    = hdec + 2*BN*HH;
    float* qs     = ctx + BN*2*HH;
    float* ssb    = qs + BN*HH;
    float* lse    = ssb + BN*TX;    // unused (kept for layout headroom)
    int*   tok    = (int*)(lse + 64);
    short* A_hi = (short*)(tok + 64);
    short* A_lo = A_hi + (size_t)BN*H3;
    short* W_hi = A_lo + (size_t)BN*H3;
    short* W_lo = W_hi + (size_t)KYV*H3;
    size_t need_bytes = (size_t)((char*)(W_lo + (size_t)KYV*H3) - (char*)d_ws);
    const bool coop = (ws_size >= need_bytes);

    hipMemsetAsync(hf, 0, BN*HH*sizeof(float), stream);
    hipMemsetAsync(hb, 0, BN*HH*sizeof(float), stream);

    // Input projections for both encoder directions
    dim3 g1(H3/64, (TX*BN)/64);
    gemm_nt_kernel<<<g1, 256, 0, stream>>>(enc_emb, inputs, EE, W_ih_f, EE, 0,
                                           b_ih_f, GI_f, H3, EE);
    gemm_nt_kernel<<<g1, 256, 0, stream>>>(enc_emb, inputs, EE, W_ih_b, EE, 0,
                                           b_ih_b, GI_b, H3, EE);

    float* out = (float*)d_out;

    if (coop) {
        // Pre-split W_lsm into bf16 hi/lo planes (once).
        wsplit_kernel<<<2048, 256, 0, stream>>>(W_lsm, W_hi, W_lo,
                                                (long)KYV*H3/4);
        // Encoder: one cooperative kernel, 64 internal steps.
        {
            void* args[] = {
                (void*)&GI_f, (void*)&GI_b,
                (void*)&W_hh_f, (void*)&b_hh_f,
                (void*)&W_hh_b, (void*)&b_hh_b,
                (void*)&hf, (void*)&hb, (void*)&enc_out
            };
            hipLaunchCooperativeKernel((void*)enc_scan_kernel, dim3(256),
                                       dim3(256), args, 0, stream);
        }
        // P_enc = enc_out @ Wa1[:,512:1536]^T
        dim3 g2(HH/64, (TX*BN)/64);
        gemm_nt_kernel<<<g2, 256, 0, stream>>>(enc_out, nullptr, 2*HH, W_a1, H3, HH,
                                               nullptr, P_enc, HH, 2*HH);
        dec_init_kernel<<<BN, 256, 0, stream>>>(hb, W_init, b_init, hdec, tok);
        // Decoder: one cooperative kernel, 32 internal steps.
        {
            void* args[] = {
                (void*)&P_enc, (void*)&enc_out,
                (void*)&W_a1, (void*)&b_a1, (void*)&W_a2, (void*)&b_a2,
                (void*)&dec_emb,
                (void*)&W_ih_d, (void*)&W_hh_d, (void*)&b_ih_d, (void*)&b_hh_d,
                (void*)&W_hi, (void*)&W_lo, (void*)&b_lsm,
                (void*)&hdec, (void*)&ctx, (void*)&qs, (void*)&ssb,
                (void*)&A_hi, (void*)&A_lo, (void*)&tok, (void*)&out
            };
            hipLaunchCooperativeKernel((void*)dec_loop_kernel, dim3(256),
                                       dim3(512), args, 0, stream);
        }
    } else {
        // -------- fallback: round-1 launch sequence --------
        for (int t = 0; t < TX; ++t) {
            const float* hfi = hf + (t & 1)*BN*HH;
            float*       hfo = hf + ((t + 1) & 1)*BN*HH;
            const float* hbi = hb + (t & 1)*BN*HH;
            float*       hbo = hb + ((t + 1) & 1)*BN*HH;
            enc_step_kernel<<<256, 256, 0, stream>>>(GI_f, GI_b, W_hh_f, b_hh_f,
                                                     W_hh_b, b_hh_b, hfi, hfo,
                                                     hbi, hbo, enc_out, t);
        }
        dim3 g2(HH/64, (TX*BN)/64);
        gemm_nt_kernel<<<g2, 256, 0, stream>>>(enc_out, nullptr, 2*HH, W_a1, H3, HH,
                                               nullptr, P_enc, HH, 2*HH);
        dec_init_kernel<<<BN, 256, 0, stream>>>(hb, W_init, b_init, hdec, tok);
        for (int s = 0; s < TY; ++s) {
            float* h_cur = hdec + (s & 1)*BN*HH;
            float* h_nxt = hdec + ((s + 1) & 1)*BN*HH;
            attn_kernel<<<BN, 256, 0, stream>>>(h_cur, P_enc, enc_out, W_a1, b_a1,
                                                W_a2, b_a2, ctx, A_hi, A_lo);
            dec_gru_kernel<<<128, 256, 0, stream>>>(dec_emb, tok, ctx, h_cur,
                                                    W_ih_d, W_hh_d, b_ih_d, b_hh_d,
                                                    h_nxt, A_hi, A_lo);
            float* lrow = out + (size_t)s*BN*KYV;
            logits_mfma_otf_kernel<<<KYV/64, 256, 0, stream>>>(A_hi, A_lo, W_lsm,
                                                               b_lsm, lrow);
            lse_argmax_sub_kernel<<<BN, 256, 0, stream>>>(lrow, tok);
        }
    }
}

// Round 3
// 10937.518 us; speedup vs baseline: 1.7689x; 1.7689x over previous
//
#include <hip/hip_runtime.h>
#include <math.h>

// Problem constants
#define TX 64
#define BN 64
#define TY 32
#define EE 256
#define HH 512
#define H3 1536
#define KYV 32000

typedef __attribute__((ext_vector_type(8))) short bf16x8;
typedef __attribute__((ext_vector_type(4))) float f32x4;
typedef __attribute__((ext_vector_type(4))) short s16x4;

__device__ __forceinline__ float4 ldf4(const float* p) { return *(const float4*)p; }
__device__ __forceinline__ float sigf(float x) { return 1.f / (1.f + expf(-x)); }

// round-to-nearest-even fp32 -> bf16 bits
__device__ __forceinline__ short f2bf(float x) {
    unsigned u = __float_as_uint(x);
    unsigned r = (u + 0x7fffu + ((u >> 16) & 1u)) >> 16;
    return (short)r;
}
__device__ __forceinline__ float bf2f(short h) {
    return __uint_as_float(((unsigned)(unsigned short)h) << 16);
}

// async 16B global -> LDS (global_load_lds_dwordx4). lds ptr must be
// wave-uniform; HW writes lane l's 16B at lds + l*16.
__device__ __forceinline__ void gload_lds16(const short* g, short* l) {
    __builtin_amdgcn_global_load_lds(
        (const __attribute__((address_space(1))) void*)(g),
        (__attribute__((address_space(3))) void*)(l), 16, 0, 0);
}

// ---------------------------------------------------------------------------
// Generic NT GEMM (fp32): C[M x N] = A[M x K] * B[N x K]^T (+bias), optional
// A row gather. Tiles 64x64, K-tile 32. M,N % 64 == 0, K % 32 == 0.
// ---------------------------------------------------------------------------
__global__ __launch_bounds__(256) void gemm_nt_kernel(
    const float* __restrict__ Abase, const int* __restrict__ gather, int lda,
    const float* __restrict__ Bbase, int ldb, int bofs,
    const float* __restrict__ bias, float* __restrict__ C, int ldc, int K)
{
    __shared__ float As[32][68];
    __shared__ float Bs[32][68];
    const int tid = threadIdx.x;
    const int n0 = blockIdx.x * 64;
    const int m0 = blockIdx.y * 64;
    const int tx = tid & 15, ty = tid >> 4;
    const int li = tid >> 2, lk = (tid & 3) * 8;
    float acc[4][4] = {};
    const float* arow = gather ? (Abase + (size_t)gather[m0 + li] * lda)
                               : (Abase + (size_t)(m0 + li) * lda);
    const float* brow = Bbase + (size_t)(n0 + li) * ldb + bofs;
    for (int kt = 0; kt < K; kt += 32) {
        float4 a0 = ldf4(arow + kt + lk);
        float4 a1 = ldf4(arow + kt + lk + 4);
        float4 b0 = ldf4(brow + kt + lk);
        float4 b1 = ldf4(brow + kt + lk + 4);
        __syncthreads();
        As[lk+0][li]=a0.x; As[lk+1][li]=a0.y; As[lk+2][li]=a0.z; As[lk+3][li]=a0.w;
        As[lk+4][li]=a1.x; As[lk+5][li]=a1.y; As[lk+6][li]=a1.z; As[lk+7][li]=a1.w;
        Bs[lk+0][li]=b0.x; Bs[lk+1][li]=b0.y; Bs[lk+2][li]=b0.z; Bs[lk+3][li]=b0.w;
        Bs[lk+4][li]=b1.x; Bs[lk+5][li]=b1.y; Bs[lk+6][li]=b1.z; Bs[lk+7][li]=b1.w;
        __syncthreads();
        #pragma unroll
        for (int k = 0; k < 32; ++k) {
            float4 av = *(const float4*)&As[k][ty*4];
            float4 bv = *(const float4*)&Bs[k][tx*4];
            acc[0][0] += av.x*bv.x; acc[0][1] += av.x*bv.y; acc[0][2] += av.x*bv.z; acc[0][3] += av.x*bv.w;
            acc[1][0] += av.y*bv.x; acc[1][1] += av.y*bv.y; acc[1][2] += av.y*bv.z; acc[1][3] += av.y*bv.w;
            acc[2][0] += av.z*bv.x; acc[2][1] += av.z*bv.y; acc[2][2] += av.z*bv.z; acc[2][3] += av.z*bv.w;
            acc[3][0] += av.w*bv.x; acc[3][1] += av.w*bv.y; acc[3][2] += av.w*bv.z; acc[3][3] += av.w*bv.w;
        }
    }
    #pragma unroll
    for (int ii = 0; ii < 4; ++ii) {
        int r = m0 + ty*4 + ii;
        #pragma unroll
        for (int jj = 0; jj < 4; ++jj) {
            int c = n0 + tx*4 + jj;
            float v = acc[ii][jj];
            if (bias) v += bias[c];
            C[(size_t)r*ldc + c] = v;
        }
    }
}

// ---------------------------------------------------------------------------
// Pack W_lsm into streaming granule order (once per launch):
// pk[T][kt][i=2t+p][lane][8 bf16], lane = q*16+m,
//   value = plane p of W[T*64 + 16t + m][kt*32 + q*8 .. +8]
// so each logits block reads a fully contiguous 294KB chunk and LDS reads are
// base + lane*16 (conflict-free).
// ---------------------------------------------------------------------------
__global__ __launch_bounds__(256) void wpack_kernel(
    const float* __restrict__ W, short* __restrict__ pk)
{
    const long id = (long)blockIdx.x*256 + threadIdx.x;   // (T,kt,t,lane)
    const long total = (long)500*48*4*64;
    if (id >= total) return;
    const int lane = (int)(id & 63);
    const long r1 = id >> 6;
    const int t = (int)(r1 & 3);
    const long r2 = r1 >> 2;
    const int kt = (int)(r2 % 48);
    const int T  = (int)(r2 / 48);
    const int m = lane & 15, q = lane >> 4;
    const int row = T*64 + t*16 + m;
    const int ks  = kt*32 + q*8;
    const float* src = W + (size_t)row*H3 + ks;
    s16x4 h0, h1, l0, l1;
    {
        float4 v = ldf4(src);
        h0.x = f2bf(v.x); l0.x = f2bf(v.x - bf2f(h0.x));
        h0.y = f2bf(v.y); l0.y = f2bf(v.y - bf2f(h0.y));
        h0.z = f2bf(v.z); l0.z = f2bf(v.z - bf2f(h0.z));
        h0.w = f2bf(v.w); l0.w = f2bf(v.w - bf2f(h0.w));
    }
    {
        float4 v = ldf4(src + 4);
        h1.x = f2bf(v.x); l1.x = f2bf(v.x - bf2f(h1.x));
        h1.y = f2bf(v.y); l1.y = f2bf(v.y - bf2f(h1.y));
        h1.z = f2bf(v.z); l1.z = f2bf(v.z - bf2f(h1.z));
        h1.w = f2bf(v.w); l1.w = f2bf(v.w - bf2f(h1.w));
    }
    const size_t gb = (((size_t)T*48 + kt)*8 + 2*t) * 512;  // shorts
    s16x4* dh = (s16x4*)(pk + gb + lane*8);
    s16x4* dl = (s16x4*)(pk + gb + 512 + lane*8);
    dh[0] = h0; dh[1] = h1;
    dl[0] = l0; dl[1] = l1;
}

// ---------------------------------------------------------------------------
// Encoder recurrent step (proven round-1 version).
// ---------------------------------------------------------------------------
__global__ __launch_bounds__(256) void enc_step_kernel(
    const float* __restrict__ GI_f, const float* __restrict__ GI_b,
    const float* __restrict__ Whh_f, const float* __restrict__ bhh_f,
    const float* __restrict__ Whh_b, const float* __restrict__ bhh_b,
    const float* __restrict__ hf_in, float* __restrict__ hf_out,
    const float* __restrict__ hb_in, float* __restrict__ hb_out,
    float* __restrict__ enc_out, int t)
{
    const int blk = blockIdx.x;
    const int dir = blk >> 7;
    const int r = blk & 127;
    const int cgp = r >> 1;
    const int bh = r & 1;
    const int sub = threadIdx.x >> 5;
    const int b = bh*32 + (threadIdx.x & 31);
    const int col = cgp*8 + sub;

    const float* GI = dir ? GI_b : GI_f;
    const float* W  = dir ? Whh_b : Whh_f;
    const float* bh_v = dir ? bhh_b : bhh_f;
    const float* hin  = dir ? hb_in : hf_in;
    float* hout = dir ? hb_out : hf_out;
    const int tstep = dir ? (TX-1-t) : t;

    const float* hrow = hin + b*HH;
    const float* wr = W + (size_t)col*HH;
    const float* wz = W + (size_t)(HH + col)*HH;
    const float* wn = W + (size_t)(2*HH + col)*HH;
    float ar = 0.f, az = 0.f, an = 0.f;
    for (int k = 0; k < HH; k += 4) {
        float4 hv = ldf4(hrow + k);
        float4 A = ldf4(wr + k), Z = ldf4(wz + k), N = ldf4(wn + k);
        ar += hv.x*A.x + hv.y*A.y + hv.z*A.z + hv.w*A.w;
        az += hv.x*Z.x + hv.y*Z.y + hv.z*Z.z + hv.w*Z.w;
        an += hv.x*N.x + hv.y*N.y + hv.z*N.z + hv.w*N.w;
    }
    size_t gbase = ((size_t)tstep*BN + b) * H3;
    float ir = GI[gbase + col];
    float iz = GI[gbase + HH + col];
    float inn = GI[gbase + 2*HH + col];
    float rr = sigf(ir + ar + bh_v[col]);
    float zz = sigf(iz + az + bh_v[HH + col]);
    float nn = tanhf(inn + rr*(an + bh_v[2*HH + col]));
    float hold = hrow[col];
    float h2 = (1.f - zz)*nn + zz*hold;
    hout[b*HH + col] = h2;
    enc_out[((size_t)tstep*BN + b)*(2*HH) + dir*HH + col] = h2;
}

// ---------------------------------------------------------------------------
// Decoder init: hidden = tanh(h_b_final @ W_init.T + b_init); tok = 1
// ---------------------------------------------------------------------------
__global__ __launch_bounds__(256) void dec_init_kernel(
    const float* __restrict__ hbf, const float* __restrict__ Wi,
    const float* __restrict__ bi, float* __restrict__ hdec, int* __restrict__ tok)
{
    const int b = blockIdx.x, tid = threadIdx.x;
    const float* hr = hbf + b*HH;
    for (int n = tid; n < HH; n += 256) {
        float acc = bi[n];
        const float* w = Wi + (size_t)n*HH;
        for (int k = 0; k < HH; k += 4) {
            float4 hv = ldf4(hr + k), wv = ldf4(w + k);
            acc += hv.x*wv.x + hv.y*wv.y + hv.z*wv.z + hv.w*wv.w;
        }
        hdec[b*HH + n] = tanhf(acc);
    }
    if (b == 0 && tid < 64) tok[tid] = 1;
}

// ---------------------------------------------------------------------------
// Attention + context. Also emits bf16 hi/lo of ctx into A[:,512:1536].
// ---------------------------------------------------------------------------
__global__ __launch_bounds__(256) void attn_kernel(
    const float* __restrict__ h, const float* __restrict__ P,
    const float* __restrict__ enc, const float* __restrict__ Wa1,
    const float* __restrict__ ba1, const float* __restrict__ Wa2,
    const float* __restrict__ ba2, float* __restrict__ ctx,
    short* __restrict__ Ahi, short* __restrict__ Alo)
{
    __shared__ float hs[HH];
    __shared__ float qsl[HH];
    __shared__ float ssl[TX];
    __shared__ float ww[TX];
    const int b = blockIdx.x, tid = threadIdx.x;
    hs[tid] = h[b*HH + tid];
    hs[tid + 256] = h[b*HH + 256 + tid];
    __syncthreads();
    for (int n = tid; n < HH; n += 256) {
        float acc = ba1[n];
        const float* w = Wa1 + (size_t)n*H3;
        for (int k = 0; k < HH; k += 4) {
            float4 wv = ldf4(w + k);
            acc += hs[k]*wv.x + hs[k+1]*wv.y + hs[k+2]*wv.z + hs[k+3]*wv.w;
        }
        qsl[n] = acc;
    }
    __syncthreads();
    {
        const int t = tid >> 2, part = tid & 3;
        const float* p = P + ((size_t)t*BN + b)*HH + part*128;
        const float* w2 = Wa2 + part*128;
        const float* q = qsl + part*128;
        float acc = 0.f;
        for (int k = 0; k < 128; k += 4) {
            float4 pv = ldf4(p + k), wv = ldf4(w2 + k);
            acc += wv.x*tanhf(q[k+0] + pv.x);
            acc += wv.y*tanhf(q[k+1] + pv.y);
            acc += wv.z*tanhf(q[k+2] + pv.z);
            acc += wv.w*tanhf(q[k+3] + pv.w);
        }
        acc += __shfl_xor(acc, 1);
        acc += __shfl_xor(acc, 2);
        if (part == 0) ssl[t] = acc + ba2[0];
    }
    __syncthreads();
    if (tid < 64) {
        float v = ssl[tid];
        float m = v;
        for (int off = 32; off; off >>= 1) m = fmaxf(m, __shfl_xor(m, off));
        float e = expf(v - m);
        float sm = e;
        for (int off = 32; off; off >>= 1) sm += __shfl_xor(sm, off);
        ww[tid] = e / sm;
    }
    __syncthreads();
    for (int c = tid; c < 2*HH; c += 256) {
        float acc = 0.f;
        #pragma unroll 4
        for (int t2 = 0; t2 < TX; ++t2)
            acc += ww[t2] * enc[((size_t)t2*BN + b)*(2*HH) + c];
        ctx[b*(2*HH) + c] = acc;
        short hi = f2bf(acc);
        Ahi[(size_t)b*H3 + HH + c] = hi;
        Alo[(size_t)b*H3 + HH + c] = f2bf(acc - bf2f(hi));
    }
}

// ---------------------------------------------------------------------------
// Decoder GRU step. Also emits bf16 hi/lo of h2 into A[:,0:512].
// ---------------------------------------------------------------------------
__global__ __launch_bounds__(256) void dec_gru_kernel(
    const float* __restrict__ demb, const int* __restrict__ tok,
    const float* __restrict__ ctx, const float* __restrict__ h,
    const float* __restrict__ Wih, const float* __restrict__ Whh,
    const float* __restrict__ bih, const float* __restrict__ bhh,
    float* __restrict__ hout, short* __restrict__ Ahi, short* __restrict__ Alo)
{
    const int col = blockIdx.x*4 + (threadIdx.x >> 6);
    const int b = threadIdx.x & 63;
    const float* emb = demb + (size_t)tok[b]*EE;
    const float* cr = ctx + b*(2*HH);
    const float* hr = h + b*HH;
    const float* wri = Wih + (size_t)col*1280;
    const float* wzi = Wih + (size_t)(HH + col)*1280;
    const float* wni = Wih + (size_t)(2*HH + col)*1280;
    float ir = 0.f, iz = 0.f, inn = 0.f;
    for (int k = 0; k < EE; k += 4) {
        float4 e = ldf4(emb + k);
        float4 A = ldf4(wri + k), Z = ldf4(wzi + k), N = ldf4(wni + k);
        ir  += e.x*A.x + e.y*A.y + e.z*A.z + e.w*A.w;
        iz  += e.x*Z.x + e.y*Z.y + e.z*Z.z + e.w*Z.w;
        inn += e.x*N.x + e.y*N.y + e.z*N.z + e.w*N.w;
    }
    for (int k = 0; k < 2*HH; k += 4) {
        float4 c = ldf4(cr + k);
        float4 A = ldf4(wri + EE + k), Z = ldf4(wzi + EE + k), N = ldf4(wni + EE + k);
        ir  += c.x*A.x + c.y*A.y + c.z*A.z + c.w*A.w;
        iz  += c.x*Z.x + c.y*Z.y + c.z*Z.z + c.w*Z.w;
        inn += c.x*N.x + c.y*N.y + c.z*N.z + c.w*N.w;
    }
    const float* wrh = Whh + (size_t)col*HH;
    const float* wzh = Whh + (size_t)(HH + col)*HH;
    const float* wnh = Whh + (size_t)(2*HH + col)*HH;
    float hrr = 0.f, hzz = 0.f, hnn = 0.f;
    for (int k = 0; k < HH; k += 4) {
        float4 hv = ldf4(hr + k);
        float4 A = ldf4(wrh + k), Z = ldf4(wzh + k), N = ldf4(wnh + k);
        hrr += hv.x*A.x + hv.y*A.y + hv.z*A.z + hv.w*A.w;
        hzz += hv.x*Z.x + hv.y*Z.y + hv.z*Z.z + hv.w*Z.w;
        hnn += hv.x*N.x + hv.y*N.y + hv.z*N.z + hv.w*N.w;
    }
    float rr = sigf(ir + bih[col] + hrr + bhh[col]);
    float zz = sigf(iz + bih[HH + col] + hzz + bhh[HH + col]);
    float nn = tanhf(inn + bih[2*HH + col] + rr*(hnn + bhh[2*HH + col]));
    float hv0 = hr[col];
    float h2 = (1.f - zz)*nn + zz*hv0;
    hout[b*HH + col] = h2;
    short hi = f2bf(h2);
    Ahi[(size_t)b*H3 + col] = hi;
    Alo[(size_t)b*H3 + col] = f2bf(h2 - bf2f(hi));
}

// ---------------------------------------------------------------------------
// Streaming MFMA logits: packed W + global_load_lds double buffer.
// Block = 4 waves, one 64-col tile. Per K-step: stage next 8KB async into
// LDS (8 x 1KB granules, 2 per wave), read current buffer (base+lane*16,
// conflict-free), 12 MFMAs. __syncthreads() drains vmcnt+lgkm (T3 minimum
// recipe). Math order identical to round-0/1 kernel -> bitwise-same output.
// ---------------------------------------------------------------------------
__global__ __launch_bounds__(256, 4) void logits_lds_kernel(
    const short* __restrict__ Ahi, const short* __restrict__ Alo,
    const short* __restrict__ Wpk, const float* __restrict__ blsm,
    float* __restrict__ outrow)
{
    __shared__ __align__(16) short sbuf[2][4096];   // 2 x 8KB
    const int tid = threadIdx.x;
    const int wave = tid >> 6, lane = tid & 63;
    const int T = blockIdx.x;
    const int n0 = T * 64;
    const int m = lane & 15, q = lane >> 4;

    const short* arow_h = Ahi + (size_t)(wave*16 + m)*H3 + q*8;
    const short* arow_l = Alo + (size_t)(wave*16 + m)*H3 + q*8;
    const short* wsrc = Wpk + (size_t)T*48*4096;    // shorts; 8KB per K-step

    f32x4 acc0 = {0,0,0,0}, acc1 = {0,0,0,0}, acc2 = {0,0,0,0}, acc3 = {0,0,0,0};

    // prologue: stage kt=0
    {
        const short* g0 = wsrc + (size_t)(2*wave)*512 + lane*8;
        gload_lds16(g0,       &sbuf[0][(2*wave  )*512]);
        gload_lds16(g0 + 512, &sbuf[0][(2*wave+1)*512]);
    }
    __syncthreads();

    int cur = 0;
    for (int kt = 0; kt < 48; ++kt) {
        if (kt < 47) {
            const short* g0 = wsrc + (size_t)(kt+1)*4096 + (2*wave)*512 + lane*8;
            gload_lds16(g0,       &sbuf[cur^1][(2*wave  )*512]);
            gload_lds16(g0 + 512, &sbuf[cur^1][(2*wave+1)*512]);
        }
        bf16x8 ah = *(const bf16x8*)(arow_h + kt*32);
        bf16x8 al = *(const bf16x8*)(arow_l + kt*32);
        const short* bb = &sbuf[cur][0] + lane*8;
        bf16x8 b0h = *(const bf16x8*)(bb + 0*512);
        bf16x8 b0l = *(const bf16x8*)(bb + 1*512);
        bf16x8 b1h = *(const bf16x8*)(bb + 2*512);
        bf16x8 b1l = *(const bf16x8*)(bb + 3*512);
        bf16x8 b2h = *(const bf16x8*)(bb + 4*512);
        bf16x8 b2l = *(const bf16x8*)(bb + 5*512);
        bf16x8 b3h = *(const bf16x8*)(bb + 6*512);
        bf16x8 b3l = *(const bf16x8*)(bb + 7*512);
        acc0 = __builtin_amdgcn_mfma_f32_16x16x32_bf16(ah, b0h, acc0, 0, 0, 0);
        acc0 = __builtin_amdgcn_mfma_f32_16x16x32_bf16(al, b0h, acc0, 0, 0, 0);
        acc0 = __builtin_amdgcn_mfma_f32_16x16x32_bf16(ah, b0l, acc0, 0, 0, 0);
        acc1 = __builtin_amdgcn_mfma_f32_16x16x32_bf16(ah, b1h, acc1, 0, 0, 0);
        acc1 = __builtin_amdgcn_mfma_f32_16x16x32_bf16(al, b1h, acc1, 0, 0, 0);
        acc1 = __builtin_amdgcn_mfma_f32_16x16x32_bf16(ah, b1l, acc1, 0, 0, 0);
        acc2 = __builtin_amdgcn_mfma_f32_16x16x32_bf16(ah, b2h, acc2, 0, 0, 0);
        acc2 = __builtin_amdgcn_mfma_f32_16x16x32_bf16(al, b2h, acc2, 0, 0, 0);
        acc2 = __builtin_amdgcn_mfma_f32_16x16x32_bf16(ah, b2l, acc2, 0, 0, 0);
        acc3 = __builtin_amdgcn_mfma_f32_16x16x32_bf16(ah, b3h, acc3, 0, 0, 0);
        acc3 = __builtin_amdgcn_mfma_f32_16x16x32_bf16(al, b3h, acc3, 0, 0, 0);
        acc3 = __builtin_amdgcn_mfma_f32_16x16x32_bf16(ah, b3l, acc3, 0, 0, 0);
        __syncthreads();   // drains vmcnt (stage) + lgkm, barriers buffer swap
        cur ^= 1;
    }

    const int row = wave*16 + q*4;
    #pragma unroll
    for (int r = 0; r < 4; ++r) {
        size_t ro = (size_t)(row + r)*KYV;
        outrow[ro + n0 +  0 + m] = acc0[r] + blsm[n0 +  0 + m];
        outrow[ro + n0 + 16 + m] = acc1[r] + blsm[n0 + 16 + m];
        outrow[ro + n0 + 32 + m] = acc2[r] + blsm[n0 + 32 + m];
        outrow[ro + n0 + 48 + m] = acc3[r] + blsm[n0 + 48 + m];
    }
}

// ---------------------------------------------------------------------------
// On-the-fly split logits (fallback when ws can't hold packed W).
// ---------------------------------------------------------------------------
__global__ __launch_bounds__(256) void logits_mfma_otf_kernel(
    const short* __restrict__ Ahi, const short* __restrict__ Alo,
    const float* __restrict__ W, const float* __restrict__ blsm,
    float* __restrict__ outrow)
{
    const int wave = threadIdx.x >> 6;
    const int lane = threadIdx.x & 63;
    const int n0 = blockIdx.x * 64;
    const int m = lane & 15;
    const int q = lane >> 4;

    const short* arow_h = Ahi + (size_t)(wave*16 + m)*H3 + q*8;
    const short* arow_l = Alo + (size_t)(wave*16 + m)*H3 + q*8;
    const float* brow = W + (size_t)(n0 + m)*H3 + q*8;

    f32x4 acc[4] = {{0,0,0,0},{0,0,0,0},{0,0,0,0},{0,0,0,0}};
    for (int kt = 0; kt < H3; kt += 32) {
        bf16x8 ah = *(const bf16x8*)(arow_h + kt);
        bf16x8 al = *(const bf16x8*)(arow_l + kt);
        float4 w0[4], w1[4];
        #pragma unroll
        for (int t = 0; t < 4; ++t) {
            const float* bp = brow + (size_t)(16*t)*H3 + kt;
            w0[t] = ldf4(bp);
            w1[t] = ldf4(bp + 4);
        }
        #pragma unroll
        for (int t = 0; t < 4; ++t) {
            float f[8] = {w0[t].x, w0[t].y, w0[t].z, w0[t].w,
                          w1[t].x, w1[t].y, w1[t].z, w1[t].w};
            bf16x8 bh, bl;
            #pragma unroll
            for (int j = 0; j < 8; ++j) {
                unsigned u = __float_as_uint(f[j]);
                unsigned hu = u & 0xffff0000u;
                bh[j] = (short)(hu >> 16);
                bl[j] = f2bf(f[j] - __uint_as_float(hu));
            }
            acc[t] = __builtin_amdgcn_mfma_f32_16x16x32_bf16(ah, bh, acc[t], 0, 0, 0);
            acc[t] = __builtin_amdgcn_mfma_f32_16x16x32_bf16(al, bh, acc[t], 0, 0, 0);
            acc[t] = __builtin_amdgcn_mfma_f32_16x16x32_bf16(ah, bl, acc[t], 0, 0, 0);
        }
    }
    const int row = wave*16 + q*4;
    #pragma unroll
    for (int r = 0; r < 4; ++r) {
        size_t ro = (size_t)(row + r)*KYV;
        outrow[ro + n0 +  0 + m] = acc[0][r] + blsm[n0 +  0 + m];
        outrow[ro + n0 + 16 + m] = acc[1][r] + blsm[n0 + 16 + m];
        outrow[ro + n0 + 32 + m] = acc[2][r] + blsm[n0 + 32 + m];
        outrow[ro + n0 + 48 + m] = acc[3][r] + blsm[n0 + 48 + m];
    }
}

// ---------------------------------------------------------------------------
// Fused per-row logsumexp + argmax + in-place (logits - lse).
// ---------------------------------------------------------------------------
__global__ __launch_bounds__(256) void lse_argmax_sub_kernel(
    float* __restrict__ rows, int* __restrict__ tok)
{
    const int b = blockIdx.x, tid = threadIdx.x;
    float4* row4 = (float4*)(rows + (size_t)b*KYV);
    float m = -1e30f, s = 0.f; int bi = 0;
    for (int i = tid; i < KYV/4; i += 256) {
        float4 v = row4[i];
        if (v.x > m) { s = s*expf(m - v.x) + 1.f; m = v.x; bi = 4*i+0; } else s += expf(v.x - m);
        if (v.y > m) { s = s*expf(m - v.y) + 1.f; m = v.y; bi = 4*i+1; } else s += expf(v.y - m);
        if (v.z > m) { s = s*expf(m - v.z) + 1.f; m = v.z; bi = 4*i+2; } else s += expf(v.z - m);
        if (v.w > m) { s = s*expf(m - v.w) + 1.f; m = v.w; bi = 4*i+3; } else s += expf(v.w - m);
    }
    for (int off = 32; off; off >>= 1) {
        float m2 = __shfl_xor(m, off);
        float s2 = __shfl_xor(s, off);
        int i2 = __shfl_xor(bi, off);
        if (m2 > m || (m2 == m && i2 < bi)) { s = s2 + s*expf(m - m2); m = m2; bi = i2; }
        else s = s + s2*expf(m2 - m);
    }
    __shared__ float ms[4], ssh[4];
    __shared__ int is_[4];
    __shared__ float l_sh;
    const int wid = tid >> 6;
    if ((tid & 63) == 0) { ms[wid] = m; ssh[wid] = s; is_[wid] = bi; }
    __syncthreads();
    if (tid == 0) {
        for (int w = 1; w < 4; ++w) {
            float m2 = ms[w], s2 = ssh[w]; int i2 = is_[w];
            if (m2 > m || (m2 == m && i2 < bi)) { s = s2 + s*expf(m - m2); m = m2; bi = i2; }
            else s = s + s2*expf(m2 - m);
        }
        l_sh = m + logf(s);
        tok[b] = bi;
    }
    __syncthreads();
    const float l = l_sh;
    for (int i = tid; i < KYV/4; i += 256) {
        float4 v = row4[i];
        v.x -= l; v.y -= l; v.z -= l; v.w -= l;
        row4[i] = v;
    }
}

// ---------------------------------------------------------------------------
extern "C" void kernel_launch(void* const* d_in, const int* in_sizes, int n_in,
                              void* d_out, int out_size, void* d_ws, size_t ws_size,
                              hipStream_t stream)
{
    const int*   inputs  = (const int*)  d_in[0];
    const float* enc_emb = (const float*)d_in[2];
    const float* W_ih_f  = (const float*)d_in[3];
    const float* W_hh_f  = (const float*)d_in[4];
    const float* b_ih_f  = (const float*)d_in[5];
    const float* b_hh_f  = (const float*)d_in[6];
    const float* W_ih_b  = (const float*)d_in[7];
    const float* W_hh_b  = (const float*)d_in[8];
    const float* b_ih_b  = (const float*)d_in[9];
    const float* b_hh_b  = (const float*)d_in[10];
    const float* W_init  = (const float*)d_in[11];
    const float* b_init  = (const float*)d_in[12];
    const float* dec_emb = (const float*)d_in[13];
    const float* W_ih_d  = (const float*)d_in[14];
    const float* W_hh_d  = (const float*)d_in[15];
    const float* b_ih_d  = (const float*)d_in[16];
    const float* b_hh_d  = (const float*)d_in[17];
    const float* W_lsm   = (const float*)d_in[18];
    const float* b_lsm   = (const float*)d_in[19];
    const float* W_a1    = (const float*)d_in[20];
    const float* b_a1    = (const float*)d_in[21];
    const float* W_a2    = (const float*)d_in[22];
    const float* b_a2    = (const float*)d_in[23];

    float* ws = (float*)d_ws;
    float* GI_f   = ws;
    float* GI_b   = GI_f + (size_t)4096*1536;
    float* enc_out= GI_b + (size_t)4096*1536;
    float* P_enc  = enc_out + (size_t)4096*1024;
    float* hf     = P_enc + (size_t)4096*512;
    float* hb     = hf + 2*BN*HH;
    float* hdec   = hb + 2*BN*HH;
    float* ctx    = hdec + 2*BN*HH;
    float* lse    = ctx + BN*2*HH;   // unused, layout headroom
    int*   tok    = (int*)(lse + 64);
    short* A_hi = (short*)(tok + 64);
    short* A_lo = A_hi + (size_t)BN*H3;
    short* W_pk = A_lo + (size_t)BN*H3;
    size_t need_bytes = (size_t)((char*)(W_pk + (size_t)KYV*H3*2) - (char*)d_ws);
    const bool packed = (ws_size >= need_bytes);

    hipMemsetAsync(hf, 0, BN*HH*sizeof(float), stream);
    hipMemsetAsync(hb, 0, BN*HH*sizeof(float), stream);

    // Input projections for both encoder directions
    dim3 g1(H3/64, (TX*BN)/64);
    gemm_nt_kernel<<<g1, 256, 0, stream>>>(enc_emb, inputs, EE, W_ih_f, EE, 0,
                                           b_ih_f, GI_f, H3, EE);
    gemm_nt_kernel<<<g1, 256, 0, stream>>>(enc_emb, inputs, EE, W_ih_b, EE, 0,
                                           b_ih_b, GI_b, H3, EE);

    if (packed) {
        // 500*48*4*64 granule-pairs / 256 threads = 24000 blocks
        wpack_kernel<<<24000, 256, 0, stream>>>(W_lsm, W_pk);
    }

    for (int t = 0; t < TX; ++t) {
        const float* hfi = hf + (t & 1)*BN*HH;
        float*       hfo = hf + ((t + 1) & 1)*BN*HH;
        const float* hbi = hb + (t & 1)*BN*HH;
        float*       hbo = hb + ((t + 1) & 1)*BN*HH;
        enc_step_kernel<<<256, 256, 0, stream>>>(GI_f, GI_b, W_hh_f, b_hh_f,
                                                 W_hh_b, b_hh_b, hfi, hfo,
                                                 hbi, hbo, enc_out, t);
    }

    dim3 g2(HH/64, (TX*BN)/64);
    gemm_nt_kernel<<<g2, 256, 0, stream>>>(enc_out, nullptr, 2*HH, W_a1, H3, HH,
                                           nullptr, P_enc, HH, 2*HH);

    dec_init_kernel<<<BN, 256, 0, stream>>>(hb, W_init, b_init, hdec, tok);

    float* out = (float*)d_out;
    for (int s = 0; s < TY; ++s) {
        float* h_cur = hdec + (s & 1)*BN*HH;
        float* h_nxt = hdec + ((s + 1) & 1)*BN*HH;
        attn_kernel<<<BN, 256, 0, stream>>>(h_cur, P_enc, enc_out, W_a1, b_a1,
                                            W_a2, b_a2, ctx, A_hi, A_lo);
        dec_gru_kernel<<<128, 256, 0, stream>>>(dec_emb, tok, ctx, h_cur,
                                                W_ih_d, W_hh_d, b_ih_d, b_hh_d,
                                                h_nxt, A_hi, A_lo);
        float* lrow = out + (size_t)s*BN*KYV;
        if (packed) {
            logits_lds_kernel<<<KYV/64, 256, 0, stream>>>(A_hi, A_lo, W_pk,
                                                          b_lsm, lrow);
        } else {
            logits_mfma_otf_kernel<<<KYV/64, 256, 0, stream>>>(A_hi, A_lo, W_lsm,
                                                               b_lsm, lrow);
        }
        lse_argmax_sub_kernel<<<BN, 256, 0, stream>>>(lrow, tok);
    }
}

// Round 4
// 10144.117 us; speedup vs baseline: 1.9072x; 1.0782x over previous
//
#include <hip/hip_runtime.h>
#include <math.h>

// Problem constants
#define TX 64
#define BN 64
#define TY 32
#define EE 256
#define HH 512
#define H3 1536
#define KYV 32000

typedef __attribute__((ext_vector_type(8))) short bf16x8;
typedef __attribute__((ext_vector_type(4))) float f32x4;
typedef __attribute__((ext_vector_type(4))) short s16x4;

__device__ __forceinline__ float4 ldf4(const float* p) { return *(const float4*)p; }
__device__ __forceinline__ float sigf(float x) { return 1.f / (1.f + expf(-x)); }

// round-to-nearest-even fp32 -> bf16 bits
__device__ __forceinline__ short f2bf(float x) {
    unsigned u = __float_as_uint(x);
    unsigned r = (u + 0x7fffu + ((u >> 16) & 1u)) >> 16;
    return (short)r;
}
__device__ __forceinline__ float bf2f(short h) {
    return __uint_as_float(((unsigned)(unsigned short)h) << 16);
}

// ---------------------------------------------------------------------------
// Generic NT GEMM (fp32): C[M x N] = A[M x K] * B[N x K]^T (+bias), optional
// A row gather. Tiles 64x64, K-tile 32. M,N % 64 == 0, K % 32 == 0.
// ---------------------------------------------------------------------------
__global__ __launch_bounds__(256) void gemm_nt_kernel(
    const float* __restrict__ Abase, const int* __restrict__ gather, int lda,
    const float* __restrict__ Bbase, int ldb, int bofs,
    const float* __restrict__ bias, float* __restrict__ C, int ldc, int K)
{
    __shared__ float As[32][68];
    __shared__ float Bs[32][68];
    const int tid = threadIdx.x;
    const int n0 = blockIdx.x * 64;
    const int m0 = blockIdx.y * 64;
    const int tx = tid & 15, ty = tid >> 4;
    const int li = tid >> 2, lk = (tid & 3) * 8;
    float acc[4][4] = {};
    const float* arow = gather ? (Abase + (size_t)gather[m0 + li] * lda)
                               : (Abase + (size_t)(m0 + li) * lda);
    const float* brow = Bbase + (size_t)(n0 + li) * ldb + bofs;
    for (int kt = 0; kt < K; kt += 32) {
        float4 a0 = ldf4(arow + kt + lk);
        float4 a1 = ldf4(arow + kt + lk + 4);
        float4 b0 = ldf4(brow + kt + lk);
        float4 b1 = ldf4(brow + kt + lk + 4);
        __syncthreads();
        As[lk+0][li]=a0.x; As[lk+1][li]=a0.y; As[lk+2][li]=a0.z; As[lk+3][li]=a0.w;
        As[lk+4][li]=a1.x; As[lk+5][li]=a1.y; As[lk+6][li]=a1.z; As[lk+7][li]=a1.w;
        Bs[lk+0][li]=b0.x; Bs[lk+1][li]=b0.y; Bs[lk+2][li]=b0.z; Bs[lk+3][li]=b0.w;
        Bs[lk+4][li]=b1.x; Bs[lk+5][li]=b1.y; Bs[lk+6][li]=b1.z; Bs[lk+7][li]=b1.w;
        __syncthreads();
        #pragma unroll
        for (int k = 0; k < 32; ++k) {
            float4 av = *(const float4*)&As[k][ty*4];
            float4 bv = *(const float4*)&Bs[k][tx*4];
            acc[0][0] += av.x*bv.x; acc[0][1] += av.x*bv.y; acc[0][2] += av.x*bv.z; acc[0][3] += av.x*bv.w;
            acc[1][0] += av.y*bv.x; acc[1][1] += av.y*bv.y; acc[1][2] += av.y*bv.z; acc[1][3] += av.y*bv.w;
            acc[2][0] += av.z*bv.x; acc[2][1] += av.z*bv.y; acc[2][2] += av.z*bv.z; acc[2][3] += av.z*bv.w;
            acc[3][0] += av.w*bv.x; acc[3][1] += av.w*bv.y; acc[3][2] += av.w*bv.z; acc[3][3] += av.w*bv.w;
        }
    }
    #pragma unroll
    for (int ii = 0; ii < 4; ++ii) {
        int r = m0 + ty*4 + ii;
        #pragma unroll
        for (int jj = 0; jj < 4; ++jj) {
            int c = n0 + tx*4 + jj;
            float v = acc[ii][jj];
            if (bias) v += bias[c];
            C[(size_t)r*ldc + c] = v;
        }
    }
}

// ---------------------------------------------------------------------------
// Pack W_lsm into streaming granule order (once per launch):
// pk[T][kt][i=2t+p][lane][8 bf16], lane = q*16+m,
//   value = plane p of W[T*64 + 16t + m][kt*32 + q*8 .. +8]
// Each wave-load of a granule (lane*16B) is one fully-coalesced 1KB fetch.
// ---------------------------------------------------------------------------
__global__ __launch_bounds__(256) void wpack_kernel(
    const float* __restrict__ W, short* __restrict__ pk)
{
    const long id = (long)blockIdx.x*256 + threadIdx.x;   // (T,kt,t,lane)
    const long total = (long)500*48*4*64;
    if (id >= total) return;
    const int lane = (int)(id & 63);
    const long r1 = id >> 6;
    const int t = (int)(r1 & 3);
    const long r2 = r1 >> 2;
    const int kt = (int)(r2 % 48);
    const int T  = (int)(r2 / 48);
    const int m = lane & 15, q = lane >> 4;
    const int row = T*64 + t*16 + m;
    const int ks  = kt*32 + q*8;
    const float* src = W + (size_t)row*H3 + ks;
    s16x4 h0, h1, l0, l1;
    {
        float4 v = ldf4(src);
        h0.x = f2bf(v.x); l0.x = f2bf(v.x - bf2f(h0.x));
        h0.y = f2bf(v.y); l0.y = f2bf(v.y - bf2f(h0.y));
        h0.z = f2bf(v.z); l0.z = f2bf(v.z - bf2f(h0.z));
        h0.w = f2bf(v.w); l0.w = f2bf(v.w - bf2f(h0.w));
    }
    {
        float4 v = ldf4(src + 4);
        h1.x = f2bf(v.x); l1.x = f2bf(v.x - bf2f(h1.x));
        h1.y = f2bf(v.y); l1.y = f2bf(v.y - bf2f(h1.y));
        h1.z = f2bf(v.z); l1.z = f2bf(v.z - bf2f(h1.z));
        h1.w = f2bf(v.w); l1.w = f2bf(v.w - bf2f(h1.w));
    }
    const size_t gb = (((size_t)T*48 + kt)*8 + 2*t) * 512;  // shorts
    s16x4* dh = (s16x4*)(pk + gb + lane*8);
    s16x4* dl = (s16x4*)(pk + gb + 512 + lane*8);
    dh[0] = h0; dh[1] = h1;
    dl[0] = l0; dl[1] = l1;
}

// ---------------------------------------------------------------------------
// Encoder recurrent step.
// ---------------------------------------------------------------------------
__global__ __launch_bounds__(256) void enc_step_kernel(
    const float* __restrict__ GI_f, const float* __restrict__ GI_b,
    const float* __restrict__ Whh_f, const float* __restrict__ bhh_f,
    const float* __restrict__ Whh_b, const float* __restrict__ bhh_b,
    const float* __restrict__ hf_in, float* __restrict__ hf_out,
    const float* __restrict__ hb_in, float* __restrict__ hb_out,
    float* __restrict__ enc_out, int t)
{
    const int blk = blockIdx.x;
    const int dir = blk >> 7;
    const int r = blk & 127;
    const int cgp = r >> 1;
    const int bh = r & 1;
    const int sub = threadIdx.x >> 5;
    const int b = bh*32 + (threadIdx.x & 31);
    const int col = cgp*8 + sub;

    const float* GI = dir ? GI_b : GI_f;
    const float* W  = dir ? Whh_b : Whh_f;
    const float* bh_v = dir ? bhh_b : bhh_f;
    const float* hin  = dir ? hb_in : hf_in;
    float* hout = dir ? hb_out : hf_out;
    const int tstep = dir ? (TX-1-t) : t;

    const float* hrow = hin + b*HH;
    const float* wr = W + (size_t)col*HH;
    const float* wz = W + (size_t)(HH + col)*HH;
    const float* wn = W + (size_t)(2*HH + col)*HH;
    float ar = 0.f, az = 0.f, an = 0.f;
    for (int k = 0; k < HH; k += 4) {
        float4 hv = ldf4(hrow + k);
        float4 A = ldf4(wr + k), Z = ldf4(wz + k), N = ldf4(wn + k);
        ar += hv.x*A.x + hv.y*A.y + hv.z*A.z + hv.w*A.w;
        az += hv.x*Z.x + hv.y*Z.y + hv.z*Z.z + hv.w*Z.w;
        an += hv.x*N.x + hv.y*N.y + hv.z*N.z + hv.w*N.w;
    }
    size_t gbase = ((size_t)tstep*BN + b) * H3;
    float ir = GI[gbase + col];
    float iz = GI[gbase + HH + col];
    float inn = GI[gbase + 2*HH + col];
    float rr = sigf(ir + ar + bh_v[col]);
    float zz = sigf(iz + az + bh_v[HH + col]);
    float nn = tanhf(inn + rr*(an + bh_v[2*HH + col]));
    float hold = hrow[col];
    float h2 = (1.f - zz)*nn + zz*hold;
    hout[b*HH + col] = h2;
    enc_out[((size_t)tstep*BN + b)*(2*HH) + dir*HH + col] = h2;
}

// ---------------------------------------------------------------------------
// Decoder init: hidden = tanh(h_b_final @ W_init.T + b_init); tok = 1
// ---------------------------------------------------------------------------
__global__ __launch_bounds__(256) void dec_init_kernel(
    const float* __restrict__ hbf, const float* __restrict__ Wi,
    const float* __restrict__ bi, float* __restrict__ hdec, int* __restrict__ tok)
{
    const int b = blockIdx.x, tid = threadIdx.x;
    const float* hr = hbf + b*HH;
    for (int n = tid; n < HH; n += 256) {
        float acc = bi[n];
        const float* w = Wi + (size_t)n*HH;
        for (int k = 0; k < HH; k += 4) {
            float4 hv = ldf4(hr + k), wv = ldf4(w + k);
            acc += hv.x*wv.x + hv.y*wv.y + hv.z*wv.z + hv.w*wv.w;
        }
        hdec[b*HH + n] = tanhf(acc);
    }
    if (b == 0 && tid < 64) tok[tid] = 1;
}

// ---------------------------------------------------------------------------
// Attention body (one block per b). Emits ctx + bf16 hi/lo into A[:,512:1536].
// ---------------------------------------------------------------------------
__device__ __forceinline__ void attn_body(
    const float* __restrict__ h, const float* __restrict__ P,
    const float* __restrict__ enc, const float* __restrict__ Wa1,
    const float* __restrict__ ba1, const float* __restrict__ Wa2,
    const float* __restrict__ ba2, float* __restrict__ ctx,
    short* __restrict__ Ahi, short* __restrict__ Alo,
    int b, int tid, float* hs, float* qsl, float* ssl, float* ww)
{
    hs[tid] = h[b*HH + tid];
    hs[tid + 256] = h[b*HH + 256 + tid];
    __syncthreads();
    for (int n = tid; n < HH; n += 256) {
        float acc = ba1[n];
        const float* w = Wa1 + (size_t)n*H3;
        for (int k = 0; k < HH; k += 4) {
            float4 wv = ldf4(w + k);
            acc += hs[k]*wv.x + hs[k+1]*wv.y + hs[k+2]*wv.z + hs[k+3]*wv.w;
        }
        qsl[n] = acc;
    }
    __syncthreads();
    {
        const int t = tid >> 2, part = tid & 3;
        const float* p = P + ((size_t)t*BN + b)*HH + part*128;
        const float* w2 = Wa2 + part*128;
        const float* q = qsl + part*128;
        float acc = 0.f;
        for (int k = 0; k < 128; k += 4) {
            float4 pv = ldf4(p + k), wv = ldf4(w2 + k);
            acc += wv.x*tanhf(q[k+0] + pv.x);
            acc += wv.y*tanhf(q[k+1] + pv.y);
            acc += wv.z*tanhf(q[k+2] + pv.z);
            acc += wv.w*tanhf(q[k+3] + pv.w);
        }
        acc += __shfl_xor(acc, 1);
        acc += __shfl_xor(acc, 2);
        if (part == 0) ssl[t] = acc + ba2[0];
    }
    __syncthreads();
    if (tid < 64) {
        float v = ssl[tid];
        float m = v;
        for (int off = 32; off; off >>= 1) m = fmaxf(m, __shfl_xor(m, off));
        float e = expf(v - m);
        float sm = e;
        for (int off = 32; off; off >>= 1) sm += __shfl_xor(sm, off);
        ww[tid] = e / sm;
    }
    __syncthreads();
    for (int c = tid; c < 2*HH; c += 256) {
        float acc = 0.f;
        #pragma unroll 4
        for (int t2 = 0; t2 < TX; ++t2)
            acc += ww[t2] * enc[((size_t)t2*BN + b)*(2*HH) + c];
        ctx[b*(2*HH) + c] = acc;
        short hi = f2bf(acc);
        Ahi[(size_t)b*H3 + HH + c] = hi;
        Alo[(size_t)b*H3 + HH + c] = f2bf(acc - bf2f(hi));
    }
}

// ---------------------------------------------------------------------------
// LSE+argmax+subtract body (one block per row).
// ---------------------------------------------------------------------------
__device__ __forceinline__ void lse_body(
    float* __restrict__ rows, int* __restrict__ tok, int b, int tid,
    float* ms, float* ssh, int* is_, float* l_sh)
{
    float4* row4 = (float4*)(rows + (size_t)b*KYV);
    float m = -1e30f, s = 0.f; int bi = 0;
    for (int i = tid; i < KYV/4; i += 256) {
        float4 v = row4[i];
        if (v.x > m) { s = s*expf(m - v.x) + 1.f; m = v.x; bi = 4*i+0; } else s += expf(v.x - m);
        if (v.y > m) { s = s*expf(m - v.y) + 1.f; m = v.y; bi = 4*i+1; } else s += expf(v.y - m);
        if (v.z > m) { s = s*expf(m - v.z) + 1.f; m = v.z; bi = 4*i+2; } else s += expf(v.z - m);
        if (v.w > m) { s = s*expf(m - v.w) + 1.f; m = v.w; bi = 4*i+3; } else s += expf(v.w - m);
    }
    for (int off = 32; off; off >>= 1) {
        float m2 = __shfl_xor(m, off);
        float s2 = __shfl_xor(s, off);
        int i2 = __shfl_xor(bi, off);
        if (m2 > m || (m2 == m && i2 < bi)) { s = s2 + s*expf(m - m2); m = m2; bi = i2; }
        else s = s + s2*expf(m2 - m);
    }
    const int wid = tid >> 6;
    if ((tid & 63) == 0) { ms[wid] = m; ssh[wid] = s; is_[wid] = bi; }
    __syncthreads();
    if (tid == 0) {
        for (int w = 1; w < 4; ++w) {
            float m2 = ms[w], s2 = ssh[w]; int i2 = is_[w];
            if (m2 > m || (m2 == m && i2 < bi)) { s = s2 + s*expf(m - m2); m = m2; bi = i2; }
            else s = s + s2*expf(m2 - m);
        }
        *l_sh = m + logf(s);
        tok[b] = bi;
    }
    __syncthreads();
    const float l = *l_sh;
    for (int i = tid; i < KYV/4; i += 256) {
        float4 v = row4[i];
        v.x -= l; v.y -= l; v.z -= l; v.w -= l;
        row4[i] = v;
    }
}

// ---------------------------------------------------------------------------
// Fused kernel: blocks [0,nlse) run lse on step-s logits (independent of
// attn); blocks [nlse, nlse+64) run attn for step s+1. nlse=0 -> attn only;
// grid 64 + nlse=64 -> lse only.
// ---------------------------------------------------------------------------
__global__ __launch_bounds__(256) void lse_attn_kernel(
    float* __restrict__ rows, int* __restrict__ tok,
    const float* __restrict__ h, const float* __restrict__ P,
    const float* __restrict__ enc, const float* __restrict__ Wa1,
    const float* __restrict__ ba1, const float* __restrict__ Wa2,
    const float* __restrict__ ba2, float* __restrict__ ctx,
    short* __restrict__ Ahi, short* __restrict__ Alo, int nlse)
{
    __shared__ float hs[HH];
    __shared__ float qsl[HH];
    __shared__ float ssl[TX];
    __shared__ float ww[TX];
    __shared__ float ms[4], ssh[4];
    __shared__ int is_[4];
    __shared__ float l_sh;
    const int B = blockIdx.x, tid = threadIdx.x;
    if (B < nlse) {
        lse_body(rows, tok, B, tid, ms, ssh, is_, &l_sh);
    } else {
        attn_body(h, P, enc, Wa1, ba1, Wa2, ba2, ctx, Ahi, Alo,
                  B - nlse, tid, hs, qsl, ssl, ww);
    }
}

// ---------------------------------------------------------------------------
// Decoder GRU step. Also emits bf16 hi/lo of h2 into A[:,0:512].
// ---------------------------------------------------------------------------
__global__ __launch_bounds__(256) void dec_gru_kernel(
    const float* __restrict__ demb, const int* __restrict__ tok,
    const float* __restrict__ ctx, const float* __restrict__ h,
    const float* __restrict__ Wih, const float* __restrict__ Whh,
    const float* __restrict__ bih, const float* __restrict__ bhh,
    float* __restrict__ hout, short* __restrict__ Ahi, short* __restrict__ Alo)
{
    const int col = blockIdx.x*4 + (threadIdx.x >> 6);
    const int b = threadIdx.x & 63;
    const float* emb = demb + (size_t)tok[b]*EE;
    const float* cr = ctx + b*(2*HH);
    const float* hr = h + b*HH;
    const float* wri = Wih + (size_t)col*1280;
    const float* wzi = Wih + (size_t)(HH + col)*1280;
    const float* wni = Wih + (size_t)(2*HH + col)*1280;
    float ir = 0.f, iz = 0.f, inn = 0.f;
    for (int k = 0; k < EE; k += 4) {
        float4 e = ldf4(emb + k);
        float4 A = ldf4(wri + k), Z = ldf4(wzi + k), N = ldf4(wni + k);
        ir  += e.x*A.x + e.y*A.y + e.z*A.z + e.w*A.w;
        iz  += e.x*Z.x + e.y*Z.y + e.z*Z.z + e.w*Z.w;
        inn += e.x*N.x + e.y*N.y + e.z*N.z + e.w*N.w;
    }
    for (int k = 0; k < 2*HH; k += 4) {
        float4 c = ldf4(cr + k);
        float4 A = ldf4(wri + EE + k), Z = ldf4(wzi + EE + k), N = ldf4(wni + EE + k);
        ir  += c.x*A.x + c.y*A.y + c.z*A.z + c.w*A.w;
        iz  += c.x*Z.x + c.y*Z.y + c.z*Z.z + c.w*Z.w;
        inn += c.x*N.x + c.y*N.y + c.z*N.z + c.w*N.w;
    }
    const float* wrh = Whh + (size_t)col*HH;
    const float* wzh = Whh + (size_t)(HH + col)*HH;
    const float* wnh = Whh + (size_t)(2*HH + col)*HH;
    float hrr = 0.f, hzz = 0.f, hnn = 0.f;
    for (int k = 0; k < HH; k += 4) {
        float4 hv = ldf4(hr + k);
        float4 A = ldf4(wrh + k), Z = ldf4(wzh + k), N = ldf4(wnh + k);
        hrr += hv.x*A.x + hv.y*A.y + hv.z*A.z + hv.w*A.w;
        hzz += hv.x*Z.x + hv.y*Z.y + hv.z*Z.z + hv.w*Z.w;
        hnn += hv.x*N.x + hv.y*N.y + hv.z*N.z + hv.w*N.w;
    }
    float rr = sigf(ir + bih[col] + hrr + bhh[col]);
    float zz = sigf(iz + bih[HH + col] + hzz + bhh[HH + col]);
    float nn = tanhf(inn + bih[2*HH + col] + rr*(hnn + bhh[2*HH + col]));
    float hv0 = hr[col];
    float h2 = (1.f - zz)*nn + zz*hv0;
    hout[b*HH + col] = h2;
    short hi = f2bf(h2);
    Ahi[(size_t)b*H3 + col] = hi;
    Alo[(size_t)b*H3 + col] = f2bf(h2 - bf2f(hi));
}

// ---------------------------------------------------------------------------
// Register-pipelined MFMA logits (barrier-free, depth-2 prefetch).
// Packed W: per (tile,kt): 8 granules of 1KB; wave-load = lane*16B, fully
// coalesced. All 10 loads for kt+1 are issued into NAMED next-registers
// before the 12 MFMAs of kt consume cur -> one RTT/iter max, hidden by TLP.
// MFMA order identical to prior rounds -> bitwise-same output.
// ---------------------------------------------------------------------------
__global__ __launch_bounds__(256, 2) void logits_pipe_kernel(
    const short* __restrict__ Ahi, const short* __restrict__ Alo,
    const short* __restrict__ Wpk, const float* __restrict__ blsm,
    float* __restrict__ outrow)
{
    const int tid = threadIdx.x;
    const int wave = tid >> 6, lane = tid & 63;
    const int T = blockIdx.x;
    const int n0 = T * 64;
    const int m = lane & 15, q = lane >> 4;

    const short* arow_h = Ahi + (size_t)(wave*16 + m)*H3 + q*8;
    const short* arow_l = Alo + (size_t)(wave*16 + m)*H3 + q*8;
    const short* wbase = Wpk + (size_t)T*48*4096 + lane*8;

    // cur operand set (kt = 0)
    bf16x8 cah  = *(const bf16x8*)(arow_h);
    bf16x8 cal  = *(const bf16x8*)(arow_l);
    bf16x8 cb0h = *(const bf16x8*)(wbase + 0*512);
    bf16x8 cb0l = *(const bf16x8*)(wbase + 1*512);
    bf16x8 cb1h = *(const bf16x8*)(wbase + 2*512);
    bf16x8 cb1l = *(const bf16x8*)(wbase + 3*512);
    bf16x8 cb2h = *(const bf16x8*)(wbase + 4*512);
    bf16x8 cb2l = *(const bf16x8*)(wbase + 5*512);
    bf16x8 cb3h = *(const bf16x8*)(wbase + 6*512);
    bf16x8 cb3l = *(const bf16x8*)(wbase + 7*512);

    f32x4 acc0 = {0,0,0,0}, acc1 = {0,0,0,0}, acc2 = {0,0,0,0}, acc3 = {0,0,0,0};

    #pragma unroll 2
    for (int kt = 0; kt < 47; ++kt) {
        const short* wn = wbase + (size_t)(kt+1)*4096;
        bf16x8 nah  = *(const bf16x8*)(arow_h + (kt+1)*32);
        bf16x8 nal  = *(const bf16x8*)(arow_l + (kt+1)*32);
        bf16x8 nb0h = *(const bf16x8*)(wn + 0*512);
        bf16x8 nb0l = *(const bf16x8*)(wn + 1*512);
        bf16x8 nb1h = *(const bf16x8*)(wn + 2*512);
        bf16x8 nb1l = *(const bf16x8*)(wn + 3*512);
        bf16x8 nb2h = *(const bf16x8*)(wn + 4*512);
        bf16x8 nb2l = *(const bf16x8*)(wn + 5*512);
        bf16x8 nb3h = *(const bf16x8*)(wn + 6*512);
        bf16x8 nb3l = *(const bf16x8*)(wn + 7*512);

        acc0 = __builtin_amdgcn_mfma_f32_16x16x32_bf16(cah, cb0h, acc0, 0, 0, 0);
        acc0 = __builtin_amdgcn_mfma_f32_16x16x32_bf16(cal, cb0h, acc0, 0, 0, 0);
        acc0 = __builtin_amdgcn_mfma_f32_16x16x32_bf16(cah, cb0l, acc0, 0, 0, 0);
        acc1 = __builtin_amdgcn_mfma_f32_16x16x32_bf16(cah, cb1h, acc1, 0, 0, 0);
        acc1 = __builtin_amdgcn_mfma_f32_16x16x32_bf16(cal, cb1h, acc1, 0, 0, 0);
        acc1 = __builtin_amdgcn_mfma_f32_16x16x32_bf16(cah, cb1l, acc1, 0, 0, 0);
        acc2 = __builtin_amdgcn_mfma_f32_16x16x32_bf16(cah, cb2h, acc2, 0, 0, 0);
        acc2 = __builtin_amdgcn_mfma_f32_16x16x32_bf16(cal, cb2h, acc2, 0, 0, 0);
        acc2 = __builtin_amdgcn_mfma_f32_16x16x32_bf16(cah, cb2l, acc2, 0, 0, 0);
        acc3 = __builtin_amdgcn_mfma_f32_16x16x32_bf16(cah, cb3h, acc3, 0, 0, 0);
        acc3 = __builtin_amdgcn_mfma_f32_16x16x32_bf16(cal, cb3h, acc3, 0, 0, 0);
        acc3 = __builtin_amdgcn_mfma_f32_16x16x32_bf16(cah, cb3l, acc3, 0, 0, 0);

        cah = nah; cal = nal;
        cb0h = nb0h; cb0l = nb0l; cb1h = nb1h; cb1l = nb1l;
        cb2h = nb2h; cb2l = nb2l; cb3h = nb3h; cb3l = nb3l;
    }
    // tail kt = 47
    acc0 = __builtin_amdgcn_mfma_f32_16x16x32_bf16(cah, cb0h, acc0, 0, 0, 0);
    acc0 = __builtin_amdgcn_mfma_f32_16x16x32_bf16(cal, cb0h, acc0, 0, 0, 0);
    acc0 = __builtin_amdgcn_mfma_f32_16x16x32_bf16(cah, cb0l, acc0, 0, 0, 0);
    acc1 = __builtin_amdgcn_mfma_f32_16x16x32_bf16(cah, cb1h, acc1, 0, 0, 0);
    acc1 = __builtin_amdgcn_mfma_f32_16x16x32_bf16(cal, cb1h, acc1, 0, 0, 0);
    acc1 = __builtin_amdgcn_mfma_f32_16x16x32_bf16(cah, cb1l, acc1, 0, 0, 0);
    acc2 = __builtin_amdgcn_mfma_f32_16x16x32_bf16(cah, cb2h, acc2, 0, 0, 0);
    acc2 = __builtin_amdgcn_mfma_f32_16x16x32_bf16(cal, cb2h, acc2, 0, 0, 0);
    acc2 = __builtin_amdgcn_mfma_f32_16x16x32_bf16(cah, cb2l, acc2, 0, 0, 0);
    acc3 = __builtin_amdgcn_mfma_f32_16x16x32_bf16(cah, cb3h, acc3, 0, 0, 0);
    acc3 = __builtin_amdgcn_mfma_f32_16x16x32_bf16(cal, cb3h, acc3, 0, 0, 0);
    acc3 = __builtin_amdgcn_mfma_f32_16x16x32_bf16(cah, cb3l, acc3, 0, 0, 0);

    const int row = wave*16 + q*4;
    #pragma unroll
    for (int r = 0; r < 4; ++r) {
        size_t ro = (size_t)(row + r)*KYV;
        outrow[ro + n0 +  0 + m] = acc0[r] + blsm[n0 +  0 + m];
        outrow[ro + n0 + 16 + m] = acc1[r] + blsm[n0 + 16 + m];
        outrow[ro + n0 + 32 + m] = acc2[r] + blsm[n0 + 32 + m];
        outrow[ro + n0 + 48 + m] = acc3[r] + blsm[n0 + 48 + m];
    }
}

// ---------------------------------------------------------------------------
// On-the-fly split logits (fallback when ws can't hold packed W).
// ---------------------------------------------------------------------------
__global__ __launch_bounds__(256) void logits_mfma_otf_kernel(
    const short* __restrict__ Ahi, const short* __restrict__ Alo,
    const float* __restrict__ W, const float* __restrict__ blsm,
    float* __restrict__ outrow)
{
    const int wave = threadIdx.x >> 6;
    const int lane = threadIdx.x & 63;
    const int n0 = blockIdx.x * 64;
    const int m = lane & 15;
    const int q = lane >> 4;

    const short* arow_h = Ahi + (size_t)(wave*16 + m)*H3 + q*8;
    const short* arow_l = Alo + (size_t)(wave*16 + m)*H3 + q*8;
    const float* brow = W + (size_t)(n0 + m)*H3 + q*8;

    f32x4 acc[4] = {{0,0,0,0},{0,0,0,0},{0,0,0,0},{0,0,0,0}};
    for (int kt = 0; kt < H3; kt += 32) {
        bf16x8 ah = *(const bf16x8*)(arow_h + kt);
        bf16x8 al = *(const bf16x8*)(arow_l + kt);
        float4 w0[4], w1[4];
        #pragma unroll
        for (int t = 0; t < 4; ++t) {
            const float* bp = brow + (size_t)(16*t)*H3 + kt;
            w0[t] = ldf4(bp);
            w1[t] = ldf4(bp + 4);
        }
        #pragma unroll
        for (int t = 0; t < 4; ++t) {
            float f[8] = {w0[t].x, w0[t].y, w0[t].z, w0[t].w,
                          w1[t].x, w1[t].y, w1[t].z, w1[t].w};
            bf16x8 bh, bl;
            #pragma unroll
            for (int j = 0; j < 8; ++j) {
                unsigned u = __float_as_uint(f[j]);
                unsigned hu = u & 0xffff0000u;
                bh[j] = (short)(hu >> 16);
                bl[j] = f2bf(f[j] - __uint_as_float(hu));
            }
            acc[t] = __builtin_amdgcn_mfma_f32_16x16x32_bf16(ah, bh, acc[t], 0, 0, 0);
            acc[t] = __builtin_amdgcn_mfma_f32_16x16x32_bf16(al, bh, acc[t], 0, 0, 0);
            acc[t] = __builtin_amdgcn_mfma_f32_16x16x32_bf16(ah, bl, acc[t], 0, 0, 0);
        }
    }
    const int row = wave*16 + q*4;
    #pragma unroll
    for (int r = 0; r < 4; ++r) {
        size_t ro = (size_t)(row + r)*KYV;
        outrow[ro + n0 +  0 + m] = acc[0][r] + blsm[n0 +  0 + m];
        outrow[ro + n0 + 16 + m] = acc[1][r] + blsm[n0 + 16 + m];
        outrow[ro + n0 + 32 + m] = acc[2][r] + blsm[n0 + 32 + m];
        outrow[ro + n0 + 48 + m] = acc[3][r] + blsm[n0 + 48 + m];
    }
}

// ---------------------------------------------------------------------------
extern "C" void kernel_launch(void* const* d_in, const int* in_sizes, int n_in,
                              void* d_out, int out_size, void* d_ws, size_t ws_size,
                              hipStream_t stream)
{
    const int*   inputs  = (const int*)  d_in[0];
    const float* enc_emb = (const float*)d_in[2];
    const float* W_ih_f  = (const float*)d_in[3];
    const float* W_hh_f  = (const float*)d_in[4];
    const float* b_ih_f  = (const float*)d_in[5];
    const float* b_hh_f  = (const float*)d_in[6];
    const float* W_ih_b  = (const float*)d_in[7];
    const float* W_hh_b  = (const float*)d_in[8];
    const float* b_ih_b  = (const float*)d_in[9];
    const float* b_hh_b  = (const float*)d_in[10];
    const float* W_init  = (const float*)d_in[11];
    const float* b_init  = (const float*)d_in[12];
    const float* dec_emb = (const float*)d_in[13];
    const float* W_ih_d  = (const float*)d_in[14];
    const float* W_hh_d  = (const float*)d_in[15];
    const float* b_ih_d  = (const float*)d_in[16];
    const float* b_hh_d  = (const float*)d_in[17];
    const float* W_lsm   = (const float*)d_in[18];
    const float* b_lsm   = (const float*)d_in[19];
    const float* W_a1    = (const float*)d_in[20];
    const float* b_a1    = (const float*)d_in[21];
    const float* W_a2    = (const float*)d_in[22];
    const float* b_a2    = (const float*)d_in[23];

    float* ws = (float*)d_ws;
    float* GI_f   = ws;
    float* GI_b   = GI_f + (size_t)4096*1536;
    float* enc_out= GI_b + (size_t)4096*1536;
    float* P_enc  = enc_out + (size_t)4096*1024;
    float* hf     = P_enc + (size_t)4096*512;
    float* hb     = hf + 2*BN*HH;
    float* hdec   = hb + 2*BN*HH;
    float* ctx    = hdec + 2*BN*HH;
    float* lse    = ctx + BN*2*HH;   // unused, layout headroom
    int*   tok    = (int*)(lse + 64);
    short* A_hi = (short*)(tok + 64);
    short* A_lo = A_hi + (size_t)BN*H3;
    short* W_pk = A_lo + (size_t)BN*H3;
    size_t need_bytes = (size_t)((char*)(W_pk + (size_t)KYV*H3*2) - (char*)d_ws);
    const bool packed = (ws_size >= need_bytes);

    hipMemsetAsync(hf, 0, BN*HH*sizeof(float), stream);
    hipMemsetAsync(hb, 0, BN*HH*sizeof(float), stream);

    // Input projections for both encoder directions
    dim3 g1(H3/64, (TX*BN)/64);
    gemm_nt_kernel<<<g1, 256, 0, stream>>>(enc_emb, inputs, EE, W_ih_f, EE, 0,
                                           b_ih_f, GI_f, H3, EE);
    gemm_nt_kernel<<<g1, 256, 0, stream>>>(enc_emb, inputs, EE, W_ih_b, EE, 0,
                                           b_ih_b, GI_b, H3, EE);

    if (packed) {
        wpack_kernel<<<24000, 256, 0, stream>>>(W_lsm, W_pk);
    }

    for (int t = 0; t < TX; ++t) {
        const float* hfi = hf + (t & 1)*BN*HH;
        float*       hfo = hf + ((t + 1) & 1)*BN*HH;
        const float* hbi = hb + (t & 1)*BN*HH;
        float*       hbo = hb + ((t + 1) & 1)*BN*HH;
        enc_step_kernel<<<256, 256, 0, stream>>>(GI_f, GI_b, W_hh_f, b_hh_f,
                                                 W_hh_b, b_hh_b, hfi, hfo,
                                                 hbi, hbo, enc_out, t);
    }

    dim3 g2(HH/64, (TX*BN)/64);
    gemm_nt_kernel<<<g2, 256, 0, stream>>>(enc_out, nullptr, 2*HH, W_a1, H3, HH,
                                           nullptr, P_enc, HH, 2*HH);

    dec_init_kernel<<<BN, 256, 0, stream>>>(hb, W_init, b_init, hdec, tok);

    float* out = (float*)d_out;

    // prologue: attn for step 0 (reads hdec[0]); nlse = 0
    lse_attn_kernel<<<64, 256, 0, stream>>>(out, tok, hdec, P_enc, enc_out,
                                            W_a1, b_a1, W_a2, b_a2, ctx,
                                            A_hi, A_lo, 0);
    for (int s = 0; s < TY; ++s) {
        float* h_cur = hdec + (s & 1)*BN*HH;
        float* h_nxt = hdec + ((s + 1) & 1)*BN*HH;
        dec_gru_kernel<<<128, 256, 0, stream>>>(dec_emb, tok, ctx, h_cur,
                                                W_ih_d, W_hh_d, b_ih_d, b_hh_d,
                                                h_nxt, A_hi, A_lo);
        float* lrow = out + (size_t)s*BN*KYV;
        if (packed) {
            logits_pipe_kernel<<<KYV/64, 256, 0, stream>>>(A_hi, A_lo, W_pk,
                                                           b_lsm, lrow);
        } else {
            logits_mfma_otf_kernel<<<KYV/64, 256, 0, stream>>>(A_hi, A_lo, W_lsm,
                                                               b_lsm, lrow);
        }
        if (s < TY-1) {
            // fused: lse(s) + attn(s+1) (reads h_nxt)
            lse_attn_kernel<<<128, 256, 0, stream>>>(lrow, tok, h_nxt, P_enc,
                                                     enc_out, W_a1, b_a1,
                                                     W_a2, b_a2, ctx,
                                                     A_hi, A_lo, 64);
        } else {
            lse_attn_kernel<<<64, 256, 0, stream>>>(lrow, tok, h_nxt, P_enc,
                                                    enc_out, W_a1, b_a1,
                                                    W_a2, b_a2, ctx,
                                                    A_hi, A_lo, 64);
        }
    }
}